// Round 1
// baseline (3597.935 us; speedup 1.0000x reference)
//
#include <hip/hip_runtime.h>
#include <hip/hip_bf16.h>
#include <math.h>

typedef __hip_bfloat16 bf16;

#define C_    384
#define NH_   12
#define HD_   32
#define MLP_  1536
#define B_    8
#define T_    12
#define N_    256
#define BT_   96
#define M_    24576        // BT_*N_
#define NINE_C 3456
#define QKV_  1152

// ---------- helpers ----------
__device__ __forceinline__ float wave_sum(float v) {
#pragma unroll
  for (int o = 32; o > 0; o >>= 1) v += __shfl_xor(v, o, 64);
  return v;
}
__device__ __forceinline__ float wave_max(float v) {
#pragma unroll
  for (int o = 32; o > 0; o >>= 1) v = fmaxf(v, __shfl_xor(v, o, 64));
  return v;
}

template <typename TO> __device__ __forceinline__ TO to_out(float v);
template <> __device__ __forceinline__ float to_out<float>(float v) { return v; }
template <> __device__ __forceinline__ bf16  to_out<bf16>(float v)  { return (bf16)v; }

// ---------- adaLN: mod = silu(c) @ w_adaln^T + b_adaln ----------
__global__ __launch_bounds__(384) void k_adaln(const float* __restrict__ c,
                                               const float* __restrict__ w,
                                               const float* __restrict__ b,
                                               float* __restrict__ mod) {
  __shared__ float sil[C_];
  const int bt = blockIdx.x, tid = threadIdx.x;
  float cv = c[bt * C_ + tid];
  sil[tid] = cv / (1.f + __expf(-cv));
  __syncthreads();
  for (int o = tid; o < NINE_C; o += 384) {
    const float* wr = w + (size_t)o * C_;
    float acc = b[o];
#pragma unroll 4
    for (int k = 0; k < C_; ++k) acc += sil[k] * wr[k];
    mod[(size_t)bt * NINE_C + o] = acc;
  }
}

// ---------- LayerNorm + adaLN modulate (spatial / mlp) ----------
// out[r] = LN(x[r]) * (1+scale[bt]) + shift[bt],  r = bt*256 + n
__global__ __launch_bounds__(256) void k_ln_mod(const float* __restrict__ x,
                                                const float* __restrict__ mod,
                                                float* __restrict__ out,
                                                int shift_chunk, int scale_chunk) {
  const int wave = threadIdx.x >> 6, lane = threadIdx.x & 63;
  const int r = blockIdx.x * 4 + wave;
  const float* xr = x + (size_t)r * C_;
  float v[6];
  float s = 0.f, ss = 0.f;
#pragma unroll
  for (int e = 0; e < 6; ++e) { v[e] = xr[lane + 64 * e]; s += v[e]; ss += v[e] * v[e]; }
  s = wave_sum(s); ss = wave_sum(ss);
  const float mean = s * (1.f / C_);
  const float var  = ss * (1.f / C_) - mean * mean;
  const float rs   = rsqrtf(var + 1e-6f);
  const int bt = r >> 8;
  const float* sh = mod + (size_t)bt * NINE_C + shift_chunk * C_;
  const float* sc = mod + (size_t)bt * NINE_C + scale_chunk * C_;
  float* orow = out + (size_t)r * C_;
#pragma unroll
  for (int e = 0; e < 6; ++e) {
    int cc = lane + 64 * e;
    orow[cc] = (v[e] - mean) * rs * (1.f + sc[cc]) + sh[cc];
  }
}

// ---------- temporal LN + modulate: gathers x[(b*T+t)*N+n] -> row rr=bn*T+t ----------
__global__ __launch_bounds__(256) void k_ln_mod_t(const float* __restrict__ x,
                                                  const float* __restrict__ mod,
                                                  float* __restrict__ out) {
  const int wave = threadIdx.x >> 6, lane = threadIdx.x & 63;
  const int rr = blockIdx.x * 4 + wave;          // rr = bn*12 + t
  const int bn = rr / T_, t = rr - bn * T_;
  const int b = bn >> 8, n = bn & 255;
  const int in_row = (b * T_ + t) * N_ + n;
  const int mrow   = b * T_ + t;
  const float* xr = x + (size_t)in_row * C_;
  float v[6];
  float s = 0.f, ss = 0.f;
#pragma unroll
  for (int e = 0; e < 6; ++e) { v[e] = xr[lane + 64 * e]; s += v[e]; ss += v[e] * v[e]; }
  s = wave_sum(s); ss = wave_sum(ss);
  const float mean = s * (1.f / C_);
  const float var  = ss * (1.f / C_) - mean * mean;
  const float rs   = rsqrtf(var + 1e-6f);
  const float* sh = mod + (size_t)mrow * NINE_C + 3 * C_;
  const float* sc = mod + (size_t)mrow * NINE_C + 4 * C_;
  float* orow = out + (size_t)rr * C_;
#pragma unroll
  for (int e = 0; e < 6; ++e) {
    int cc = lane + 64 * e;
    orow[cc] = (v[e] - mean) * rs * (1.f + sc[cc]) + sh[cc];
  }
}

// ---------- generic GEMM: out[M,N] = act(A[M,K] @ W[N,K]^T + bias) ----------
// 64x64 tile, BK=16, 256 threads, 4x4 per thread, fp32 accumulate.
template <typename TA, typename TO, int ACT>
__global__ __launch_bounds__(256) void gemm_bt(const TA* __restrict__ A,
                                               const float* __restrict__ W,
                                               const float* __restrict__ bias,
                                               TO* __restrict__ out,
                                               int M, int N, int K) {
  __shared__ float As[16][65];
  __shared__ float Ws[16][65];
  const int tid = threadIdx.x;
  const int tm = tid & 15, tn = tid >> 4;
  const int m0 = blockIdx.y * 64, n0 = blockIdx.x * 64;
  const int kk = tid & 15;       // k within tile for staging
  const int rr = tid >> 4;       // row group for staging
  float acc[4][4] = {};
  for (int k0 = 0; k0 < K; k0 += 16) {
#pragma unroll
    for (int p = 0; p < 4; ++p) {
      int m = rr + 16 * p;
      As[kk][m] = (float)A[(size_t)(m0 + m) * K + k0 + kk];
      Ws[kk][m] = W[(size_t)(n0 + m) * K + k0 + kk];
    }
    __syncthreads();
#pragma unroll
    for (int k = 0; k < 16; ++k) {
      float a[4], b[4];
#pragma unroll
      for (int i = 0; i < 4; ++i) a[i] = As[k][tm * 4 + i];
#pragma unroll
      for (int j = 0; j < 4; ++j) b[j] = Ws[k][tn * 4 + j];
#pragma unroll
      for (int i = 0; i < 4; ++i)
#pragma unroll
        for (int j = 0; j < 4; ++j) acc[i][j] += a[i] * b[j];
    }
    __syncthreads();
  }
#pragma unroll
  for (int i = 0; i < 4; ++i) {
    int m = m0 + tm * 4 + i;
#pragma unroll
    for (int j = 0; j < 4; ++j) {
      int n = n0 + tn * 4 + j;
      float v = acc[i][j] + bias[n];
      if (ACT == 1) v = 0.5f * v * (1.f + erff(v * 0.70710678118654752f));
      out[(size_t)m * N + n] = to_out<TO>(v);
    }
  }
}

// ---------- spatial attention: softmax(q k^T * scale + bias) -> attn map ----------
// one block per (bt, h); thread j owns column j; loop over query rows i.
__global__ __launch_bounds__(256) void k_attn_sm(const bf16* __restrict__ qkv,
                                                 const float* __restrict__ bias,
                                                 float* __restrict__ attn) {
  __shared__ float qs[N_][HD_];
  __shared__ float ks[N_][HD_ + 1];
  __shared__ float redm[4], redl[4];
  const int blk = blockIdx.x;
  const int bt = blk / NH_, h = blk - bt * NH_;
  const int tid = threadIdx.x;
  for (int idx = tid; idx < N_ * HD_; idx += 256) {
    int j = idx >> 5, d = idx & 31;
    const bf16* row = qkv + (size_t)(bt * N_ + j) * QKV_ + h * HD_ + d;
    qs[j][d] = (float)row[0];
    ks[j][d] = (float)row[C_];
  }
  __syncthreads();
  const int wave = tid >> 6, lane = tid & 63;
  float kreg[HD_];
#pragma unroll
  for (int d = 0; d < HD_; ++d) kreg[d] = ks[tid][d];
  const float scale = 0.17677669529663687f;   // 1/sqrt(32)
  float* arow_base = attn + (size_t)blk * N_ * N_;
  const float* brow_base = bias + (size_t)h * N_ * N_;
  for (int i = 0; i < N_; ++i) {
    float s = 0.f;
#pragma unroll
    for (int d = 0; d < HD_; ++d) s += qs[i][d] * kreg[d];
    s = s * scale + brow_base[i * N_ + tid];
    float m = wave_max(s);
    if (lane == 0) redm[wave] = m;
    __syncthreads();
    m = fmaxf(fmaxf(redm[0], redm[1]), fmaxf(redm[2], redm[3]));
    float p = __expf(s - m);
    float l = wave_sum(p);
    if (lane == 0) redl[wave] = l;
    __syncthreads();
    l = (redl[0] + redl[1]) + (redl[2] + redl[3]);
    arow_base[i * N_ + tid] = p / l;
  }
}

// ---------- spatial attn @ v : out[bt*N+i][h*32+d] ----------
__global__ __launch_bounds__(256) void k_attn_v(const bf16* __restrict__ qkv,
                                                const float* __restrict__ attn,
                                                float* __restrict__ out) {
  __shared__ float vs[N_][HD_];
  const int blk = blockIdx.x;
  const int bt = blk / NH_, h = blk - bt * NH_;
  const int tid = threadIdx.x;
  for (int idx = tid; idx < N_ * HD_; idx += 256) {
    int j = idx >> 5, d = idx & 31;
    vs[j][d] = (float)qkv[(size_t)(bt * N_ + j) * QKV_ + 2 * C_ + h * HD_ + d];
  }
  __syncthreads();
  float acc[HD_] = {};
  const float4* arow = (const float4*)(attn + ((size_t)blk * N_ + tid) * N_);
  for (int j4 = 0; j4 < N_ / 4; ++j4) {
    float4 p = arow[j4];
    int j = j4 * 4;
#pragma unroll
    for (int d = 0; d < HD_; ++d) acc[d] += p.x * vs[j][d];
#pragma unroll
    for (int d = 0; d < HD_; ++d) acc[d] += p.y * vs[j + 1][d];
#pragma unroll
    for (int d = 0; d < HD_; ++d) acc[d] += p.z * vs[j + 2][d];
#pragma unroll
    for (int d = 0; d < HD_; ++d) acc[d] += p.w * vs[j + 3][d];
  }
  float* orow = out + (size_t)(bt * N_ + tid) * C_ + h * HD_;
#pragma unroll
  for (int d = 0; d < HD_; ++d) orow[d] = acc[d];
}

// ---------- temporal attention (T=12, no bias) ----------
// one block of 64 per (bn, h); thread t handles query row t.
__global__ __launch_bounds__(64) void k_attn_t(const bf16* __restrict__ qkv,
                                               float* __restrict__ out) {
  __shared__ float q[T_][HD_], k[T_][HD_], v[T_][HD_];
  const int blk = blockIdx.x;
  const int bn = blk / NH_, h = blk - bn * NH_;
  const int tid = threadIdx.x;
  for (int idx = tid; idx < T_ * 3 * HD_; idx += 64) {
    int t = idx / 96, rem = idx - t * 96;
    int s = rem >> 5, d = rem & 31;
    float val = (float)qkv[(size_t)(bn * T_ + t) * QKV_ + s * C_ + h * HD_ + d];
    if (s == 0) q[t][d] = val;
    else if (s == 1) k[t][d] = val;
    else v[t][d] = val;
  }
  __syncthreads();
  if (tid < T_) {
    const int i = tid;
    float sv[T_];
    float m = -1e30f;
#pragma unroll
    for (int j = 0; j < T_; ++j) {
      float s = 0.f;
#pragma unroll
      for (int d = 0; d < HD_; ++d) s += q[i][d] * k[j][d];
      s *= 0.17677669529663687f;
      sv[j] = s; m = fmaxf(m, s);
    }
    float l = 0.f;
#pragma unroll
    for (int j = 0; j < T_; ++j) { sv[j] = __expf(sv[j] - m); l += sv[j]; }
    const float inv = 1.f / l;
    float o[HD_];
#pragma unroll
    for (int d = 0; d < HD_; ++d) o[d] = 0.f;
#pragma unroll
    for (int j = 0; j < T_; ++j)
#pragma unroll
      for (int d = 0; d < HD_; ++d) o[d] += sv[j] * v[j][d];
    float* orow = out + (size_t)(bn * T_ + i) * C_ + h * HD_;
#pragma unroll
    for (int d = 0; d < HD_; ++d) orow[d] = o[d] * inv;
  }
}

// ---------- residual with gate: out = base + gate[bt]*add ----------
__global__ __launch_bounds__(128) void k_resid(const float* __restrict__ base,
                                               const float* __restrict__ add,
                                               const float* __restrict__ mod,
                                               float* __restrict__ out,
                                               int gate_chunk) {
  const int cc = blockIdx.x * 128 + threadIdx.x;
  const int r = blockIdx.y;
  const int bt = r >> 8;
  const size_t idx = (size_t)r * C_ + cc;
  out[idx] = base[idx] + mod[(size_t)bt * NINE_C + gate_chunk * C_ + cc] * add[idx];
}

// ---------- temporal residual scatter: x[bt*N+n] += gate_t[bt]*proj_t[(b*N+n)*T+t] ----------
__global__ __launch_bounds__(128) void k_resid_t(const float* __restrict__ add,
                                                 const float* __restrict__ mod,
                                                 float* __restrict__ out) {
  const int cc = blockIdx.x * 128 + threadIdx.x;
  const int r = blockIdx.y;                 // r = bt*256 + n
  const int bt = r >> 8, n = r & 255;
  const int b = bt / T_, t = bt - b * T_;
  const size_t src = ((size_t)(b * N_ + n) * T_ + t) * C_ + cc;
  const size_t dst = (size_t)r * C_ + cc;
  out[dst] += mod[(size_t)bt * NINE_C + 5 * C_ + cc] * add[src];
}

extern "C" void kernel_launch(void* const* d_in, const int* in_sizes, int n_in,
                              void* d_out, int out_size, void* d_ws, size_t ws_size,
                              hipStream_t stream) {
  const float* x_in   = (const float*)d_in[0];
  const float* c_in   = (const float*)d_in[1];
  const float* relb   = (const float*)d_in[2];
  const float* w_ada  = (const float*)d_in[3];
  const float* b_ada  = (const float*)d_in[4];
  const float* wqkv_s = (const float*)d_in[5];
  const float* bqkv_s = (const float*)d_in[6];
  const float* wproj_s= (const float*)d_in[7];
  const float* bproj_s= (const float*)d_in[8];
  const float* wqkv_t = (const float*)d_in[9];
  const float* bqkv_t = (const float*)d_in[10];
  const float* wproj_t= (const float*)d_in[11];
  const float* bproj_t= (const float*)d_in[12];
  const float* w1     = (const float*)d_in[13];
  const float* b1     = (const float*)d_in[14];
  const float* w2     = (const float*)d_in[15];
  const float* b2     = (const float*)d_in[16];

  float* Xout = (float*)d_out;                       // 24576*384 floats
  float* attn = (float*)d_out + (size_t)M_ * C_;     // 96*12*256*256 floats

  // workspace layout (bytes): mod 1,331,200 | Bbuf 37,748,736 | Abuf(bf16) 75,497,472 | Cbuf 37,748,736
  char* ws = (char*)d_ws;
  float* mod  = (float*)ws;
  float* Bbuf = (float*)(ws + 1331200);
  bf16*  Abuf = (bf16*) (ws + 1331200 + 37748736);
  float* Cbuf = (float*)(ws + 1331200 + 37748736 + 75497472);

  // 1. adaLN modulation
  k_adaln<<<BT_, 384, 0, stream>>>(c_in, w_ada, b_ada, mod);

  // 2. spatial: LN+mod -> qkv -> attention -> proj -> gated residual
  k_ln_mod<<<M_ / 4, 256, 0, stream>>>(x_in, mod, Bbuf, 0, 1);
  gemm_bt<float, bf16, 0><<<dim3(QKV_ / 64, M_ / 64), 256, 0, stream>>>(
      Bbuf, wqkv_s, bqkv_s, Abuf, M_, QKV_, C_);
  k_attn_sm<<<BT_ * NH_, 256, 0, stream>>>(Abuf, relb, attn);
  k_attn_v<<<BT_ * NH_, 256, 0, stream>>>(Abuf, attn, Bbuf);
  gemm_bt<float, float, 0><<<dim3(C_ / 64, M_ / 64), 256, 0, stream>>>(
      Bbuf, wproj_s, bproj_s, Cbuf, M_, C_, C_);
  k_resid<<<dim3(3, M_), 128, 0, stream>>>(x_in, Cbuf, mod, Xout, 2);

  // 3. temporal: gather-LN -> qkv -> attention -> proj -> scatter residual
  k_ln_mod_t<<<M_ / 4, 256, 0, stream>>>(Xout, mod, Bbuf);
  gemm_bt<float, bf16, 0><<<dim3(QKV_ / 64, M_ / 64), 256, 0, stream>>>(
      Bbuf, wqkv_t, bqkv_t, Abuf, M_, QKV_, C_);
  k_attn_t<<<B_ * N_ * NH_, 64, 0, stream>>>(Abuf, Bbuf);
  gemm_bt<float, float, 0><<<dim3(C_ / 64, M_ / 64), 256, 0, stream>>>(
      Bbuf, wproj_t, bproj_t, Cbuf, M_, C_, C_);
  k_resid_t<<<dim3(3, M_), 128, 0, stream>>>(Cbuf, mod, Xout);

  // 4. MLP: LN+mod -> GEMM+GELU -> GEMM -> gated residual
  k_ln_mod<<<M_ / 4, 256, 0, stream>>>(Xout, mod, Bbuf, 6, 7);
  gemm_bt<float, bf16, 1><<<dim3(MLP_ / 64, M_ / 64), 256, 0, stream>>>(
      Bbuf, w1, b1, Abuf, M_, MLP_, C_);
  gemm_bt<bf16, float, 0><<<dim3(C_ / 64, M_ / 64), 256, 0, stream>>>(
      Abuf, w2, b2, Cbuf, M_, C_, MLP_);
  k_resid<<<dim3(3, M_), 128, 0, stream>>>(Xout, Cbuf, mod, Xout, 8);
}

// Round 3
// 1029.354 us; speedup vs baseline: 3.4953x; 3.4953x over previous
//
#include <hip/hip_runtime.h>
#include <hip/hip_bf16.h>
#include <math.h>

typedef __bf16 bf16;
typedef __bf16 bf16x8 __attribute__((ext_vector_type(8)));
typedef __bf16 bf16x4 __attribute__((ext_vector_type(4)));
typedef float  f32x4  __attribute__((ext_vector_type(4)));

#define C_    384
#define NH_   12
#define HD_   32
#define MLP_  1536
#define B_    8
#define T_    12
#define N_    256
#define BT_   96
#define M_    24576
#define NINE_C 3456
#define QKV_  1152

__device__ __forceinline__ float wave_sum(float v) {
#pragma unroll
  for (int o = 32; o > 0; o >>= 1) v += __shfl_xor(v, o, 64);
  return v;
}
__device__ __forceinline__ float wave_max(float v) {
#pragma unroll
  for (int o = 32; o > 0; o >>= 1) v = fmaxf(v, __shfl_xor(v, o, 64));
  return v;
}

template <typename TO> __device__ __forceinline__ TO to_out(float v);
template <> __device__ __forceinline__ float to_out<float>(float v) { return v; }
template <> __device__ __forceinline__ bf16  to_out<bf16>(float v)  { return (bf16)v; }

// ---------- f32 -> bf16 weight conversion ----------
__global__ __launch_bounds__(256) void k_f2b(const float* __restrict__ in,
                                             bf16* __restrict__ out, int n4) {
  int i = blockIdx.x * 256 + threadIdx.x;
  if (i < n4) {
    float4 v = ((const float4*)in)[i];
    bf16x4 o;
    o[0] = (bf16)v.x; o[1] = (bf16)v.y; o[2] = (bf16)v.z; o[3] = (bf16)v.w;
    ((bf16x4*)out)[i] = o;
  }
}

// ---------- adaLN: mod = silu(c) @ w_adaln^T + b_adaln ----------
__global__ __launch_bounds__(384) void k_adaln(const float* __restrict__ c,
                                               const float* __restrict__ w,
                                               const float* __restrict__ b,
                                               float* __restrict__ mod) {
  __shared__ float sil[C_];
  const int bt = blockIdx.x, tid = threadIdx.x;
  float cv = c[bt * C_ + tid];
  sil[tid] = cv / (1.f + __expf(-cv));
  __syncthreads();
  for (int o = tid; o < NINE_C; o += 384) {
    const float* wr = w + (size_t)o * C_;
    float acc = b[o];
#pragma unroll 4
    for (int k = 0; k < C_; ++k) acc += sil[k] * wr[k];
    mod[(size_t)bt * NINE_C + o] = acc;
  }
}

// ---------- LayerNorm + adaLN modulate -> bf16 ----------
__global__ __launch_bounds__(256) void k_ln_mod(const float* __restrict__ x,
                                                const float* __restrict__ mod,
                                                bf16* __restrict__ out,
                                                int shift_chunk, int scale_chunk) {
  const int wave = threadIdx.x >> 6, lane = threadIdx.x & 63;
  const int r = blockIdx.x * 4 + wave;
  const float* xr = x + (size_t)r * C_;
  float v[6];
  float s = 0.f, ss = 0.f;
#pragma unroll
  for (int e = 0; e < 6; ++e) { v[e] = xr[lane + 64 * e]; s += v[e]; ss += v[e] * v[e]; }
  s = wave_sum(s); ss = wave_sum(ss);
  const float mean = s * (1.f / C_);
  const float var  = ss * (1.f / C_) - mean * mean;
  const float rs   = rsqrtf(var + 1e-6f);
  const int bt = r >> 8;
  const float* sh = mod + (size_t)bt * NINE_C + shift_chunk * C_;
  const float* sc = mod + (size_t)bt * NINE_C + scale_chunk * C_;
  bf16* orow = out + (size_t)r * C_;
#pragma unroll
  for (int e = 0; e < 6; ++e) {
    int cc = lane + 64 * e;
    orow[cc] = (bf16)((v[e] - mean) * rs * (1.f + sc[cc]) + sh[cc]);
  }
}

// ---------- temporal LN + modulate (gather) -> bf16 ----------
__global__ __launch_bounds__(256) void k_ln_mod_t(const float* __restrict__ x,
                                                  const float* __restrict__ mod,
                                                  bf16* __restrict__ out) {
  const int wave = threadIdx.x >> 6, lane = threadIdx.x & 63;
  const int rr = blockIdx.x * 4 + wave;          // rr = bn*12 + t
  const int bn = rr / T_, t = rr - bn * T_;
  const int b = bn >> 8, n = bn & 255;
  const int in_row = (b * T_ + t) * N_ + n;
  const int mrow   = b * T_ + t;
  const float* xr = x + (size_t)in_row * C_;
  float v[6];
  float s = 0.f, ss = 0.f;
#pragma unroll
  for (int e = 0; e < 6; ++e) { v[e] = xr[lane + 64 * e]; s += v[e]; ss += v[e] * v[e]; }
  s = wave_sum(s); ss = wave_sum(ss);
  const float mean = s * (1.f / C_);
  const float var  = ss * (1.f / C_) - mean * mean;
  const float rs   = rsqrtf(var + 1e-6f);
  const float* sh = mod + (size_t)mrow * NINE_C + 3 * C_;
  const float* sc = mod + (size_t)mrow * NINE_C + 4 * C_;
  bf16* orow = out + (size_t)rr * C_;
#pragma unroll
  for (int e = 0; e < 6; ++e) {
    int cc = lane + 64 * e;
    orow[cc] = (bf16)((v[e] - mean) * rs * (1.f + sc[cc]) + sh[cc]);
  }
}

// ---------- MFMA GEMM: out[M,N] = act(A[M,K](bf16) @ W[N,K]^T(bf16) + bias) ----------
// 128x128 tile, BK=64, 256 threads (4 waves, each a 64x64 quadrant).
template <typename TO, int ACT>
__global__ __launch_bounds__(256) void mfma_gemm(const bf16* __restrict__ A,
                                                 const bf16* __restrict__ W,
                                                 const float* __restrict__ bias,
                                                 TO* __restrict__ out,
                                                 int M, int N, int K) {
  __shared__ bf16 As[128 * 64];
  __shared__ bf16 Bs[128 * 64];
  const int tid = threadIdx.x;
  const int w = tid >> 6, l = tid & 63;
  const int m0 = blockIdx.y * 128, n0 = blockIdx.x * 128;
  const int wr = w >> 1, wc = w & 1;
  f32x4 acc[4][4];
#pragma unroll
  for (int mi = 0; mi < 4; ++mi)
#pragma unroll
    for (int nj = 0; nj < 4; ++nj) acc[mi][nj] = (f32x4){0.f, 0.f, 0.f, 0.f};

  const int srow = tid >> 3;   // 0..31 (+32 per round)
  const int sc_  = tid & 7;    // chunk 0..7

  for (int k0 = 0; k0 < K; k0 += 64) {
#pragma unroll
    for (int r = 0; r < 4; ++r) {
      int row = srow + 32 * r;
      bf16x8 av = *(const bf16x8*)(A + (size_t)(m0 + row) * K + k0 + sc_ * 8);
      bf16x8 bv = *(const bf16x8*)(W + (size_t)(n0 + row) * K + k0 + sc_ * 8);
      int sw = (sc_ ^ (row & 7)) << 4;
      *(bf16x8*)((char*)As + row * 128 + sw) = av;
      *(bf16x8*)((char*)Bs + row * 128 + sw) = bv;
    }
    __syncthreads();
#pragma unroll
    for (int kt = 0; kt < 2; ++kt) {
      bf16x8 a[4], b[4];
      const int cc = kt * 4 + (l >> 4);
#pragma unroll
      for (int mi = 0; mi < 4; ++mi) {
        int row = wr * 64 + mi * 16 + (l & 15);
        a[mi] = *(const bf16x8*)((const char*)As + row * 128 + ((cc ^ (row & 7)) << 4));
      }
#pragma unroll
      for (int nj = 0; nj < 4; ++nj) {
        int row = wc * 64 + nj * 16 + (l & 15);
        b[nj] = *(const bf16x8*)((const char*)Bs + row * 128 + ((cc ^ (row & 7)) << 4));
      }
#pragma unroll
      for (int mi = 0; mi < 4; ++mi)
#pragma unroll
        for (int nj = 0; nj < 4; ++nj)
          acc[mi][nj] = __builtin_amdgcn_mfma_f32_16x16x32_bf16(a[mi], b[nj], acc[mi][nj], 0, 0, 0);
    }
    __syncthreads();
  }
#pragma unroll
  for (int nj = 0; nj < 4; ++nj) {
    int col = n0 + wc * 64 + nj * 16 + (l & 15);
    float bv = bias[col];
#pragma unroll
    for (int mi = 0; mi < 4; ++mi) {
#pragma unroll
      for (int q = 0; q < 4; ++q) {
        int rrow = m0 + wr * 64 + mi * 16 + (l >> 4) * 4 + q;
        float v = acc[mi][nj][q] + bv;
        if (ACT == 1) v = 0.5f * v * (1.f + erff(v * 0.70710678118654752f));
        out[(size_t)rrow * N + col] = to_out<TO>(v);
      }
    }
  }
}

// ---------- spatial attention softmax -> attn map (wave-parallel) ----------
__global__ __launch_bounds__(256) void k_attn_sm2(const bf16* __restrict__ qkv,
                                                  const float* __restrict__ bias,
                                                  float* __restrict__ attn) {
  __shared__ float kT[32][256];
  __shared__ bf16  qs[256][32];
  const int blk = blockIdx.x;
  const int bt = blk / NH_, h = blk - bt * NH_;
  const int tid = threadIdx.x;
#pragma unroll
  for (int r = 0; r < 4; ++r) {
    int id = tid + 256 * r;                  // 1024 chunks
    int row = id >> 2, c = id & 3;
    const bf16* src = qkv + (size_t)(bt * N_ + row) * QKV_ + h * HD_ + c * 8;
    bf16x8 qv = *(const bf16x8*)src;
    *(bf16x8*)&qs[row][c * 8] = qv;
    bf16x8 kv = *(const bf16x8*)(src + C_);
#pragma unroll
    for (int i = 0; i < 8; ++i) kT[c * 8 + i][row] = (float)kv[i];
  }
  __syncthreads();
  const int w = tid >> 6, l = tid & 63;
  const int l4 = l * 4;
  const float scale = 0.17677669529663687f;
  const float* bb = bias + (size_t)h * N_ * N_;
  float* ab = attn + (size_t)blk * N_ * N_;
  for (int g = 0; g < 16; ++g) {
    const int i0 = w * 64 + g * 4;
    float acc[4][4];
#pragma unroll
    for (int rr = 0; rr < 4; ++rr)
#pragma unroll
      for (int cc = 0; cc < 4; ++cc) acc[rr][cc] = 0.f;
    for (int d2 = 0; d2 < 16; ++d2) {
      const float4 k0 = *(const float4*)&kT[2 * d2][l4];
      const float4 k1 = *(const float4*)&kT[2 * d2 + 1][l4];
#pragma unroll
      for (int rr = 0; rr < 4; ++rr) {
        uint32_t qp = *(const uint32_t*)&qs[i0 + rr][2 * d2];
        float qa = __uint_as_float(qp << 16);
        float qb = __uint_as_float(qp & 0xffff0000u);
        acc[rr][0] += qa * k0.x + qb * k1.x;
        acc[rr][1] += qa * k0.y + qb * k1.y;
        acc[rr][2] += qa * k0.z + qb * k1.z;
        acc[rr][3] += qa * k0.w + qb * k1.w;
      }
    }
#pragma unroll
    for (int rr = 0; rr < 4; ++rr) {
      const float4 bv = *(const float4*)&bb[(size_t)(i0 + rr) * N_ + l4];
      float s0 = acc[rr][0] * scale + bv.x;
      float s1 = acc[rr][1] * scale + bv.y;
      float s2 = acc[rr][2] * scale + bv.z;
      float s3 = acc[rr][3] * scale + bv.w;
      float m = wave_max(fmaxf(fmaxf(s0, s1), fmaxf(s2, s3)));
      float p0 = __expf(s0 - m), p1 = __expf(s1 - m);
      float p2 = __expf(s2 - m), p3 = __expf(s3 - m);
      float lsum = wave_sum((p0 + p1) + (p2 + p3));
      float inv = __frcp_rn(lsum);
      float4 o; o.x = p0 * inv; o.y = p1 * inv; o.z = p2 * inv; o.w = p3 * inv;
      *(float4*)&ab[(size_t)(i0 + rr) * N_ + l4] = o;
    }
  }
}

// ---------- spatial P@V via MFMA: out[bt*N+i][h*32+d] = sum_j P[i][j] V[j][d] ----------
// One block (256 thr, 4 waves) per (bt,h). V transposed in LDS (XOR-swizzled),
// B-fragments hoisted to registers, P read fp32 from attn map, cvt to bf16.
__global__ __launch_bounds__(256) void k_attn_pv(const bf16* __restrict__ qkv,
                                                 const float* __restrict__ attn,
                                                 bf16* __restrict__ out) {
  __shared__ bf16 Vt[32 * 256];        // [d][k], rows 512B, 16B chunks XOR-swizzled
  const int blk = blockIdx.x;
  const int bt = blk / NH_, h = blk - bt * NH_;
  const int tid = threadIdx.x;
#pragma unroll
  for (int r = 0; r < 4; ++r) {
    int id = tid + 256 * r;            // 1024 = 256 rows x 4 chunks
    int j = id >> 2, c = id & 3;       // j = K index, dims c*8..c*8+7
    bf16x8 vv = *(const bf16x8*)(qkv + (size_t)(bt * N_ + j) * QKV_ + 2 * C_ + h * HD_ + c * 8);
    int kc = j >> 3, ke = j & 7;
#pragma unroll
    for (int i = 0; i < 8; ++i) {
      int d = c * 8 + i;
      *(bf16*)((char*)Vt + d * 512 + ((kc ^ (d & 7)) << 4) + ke * 2) = vv[i];
    }
  }
  __syncthreads();
  const int w = tid >> 6, l = tid & 63;
  const int i0 = w * 64;
  const int dn = l & 15, kg = l >> 4;
  // B fragments: b[nj][kt] = V[k = kt*32 + kg*8 + e][d = nj*16 + dn]
  bf16x8 bfr[2][8];
#pragma unroll
  for (int nj = 0; nj < 2; ++nj) {
    int d = nj * 16 + dn;
#pragma unroll
    for (int kt = 0; kt < 8; ++kt) {
      int kc = kt * 4 + kg;
      bfr[nj][kt] = *(const bf16x8*)((const char*)Vt + d * 512 + ((kc ^ (d & 7)) << 4));
    }
  }
  f32x4 acc[4][2];
#pragma unroll
  for (int mi = 0; mi < 4; ++mi)
#pragma unroll
    for (int nj = 0; nj < 2; ++nj) acc[mi][nj] = (f32x4){0.f, 0.f, 0.f, 0.f};
  const float* Pbase = attn + (size_t)blk * N_ * N_;
#pragma unroll
  for (int kt = 0; kt < 8; ++kt) {
#pragma unroll
    for (int mi = 0; mi < 4; ++mi) {
      int row = i0 + mi * 16 + dn;     // A: row = lane&15, k = kg*8 + e
      const float* pr = Pbase + (size_t)row * N_ + kt * 32 + kg * 8;
      float4 p0 = *(const float4*)pr;
      float4 p1 = *(const float4*)(pr + 4);
      bf16x8 a;
      a[0] = (bf16)p0.x; a[1] = (bf16)p0.y; a[2] = (bf16)p0.z; a[3] = (bf16)p0.w;
      a[4] = (bf16)p1.x; a[5] = (bf16)p1.y; a[6] = (bf16)p1.z; a[7] = (bf16)p1.w;
      acc[mi][0] = __builtin_amdgcn_mfma_f32_16x16x32_bf16(a, bfr[0][kt], acc[mi][0], 0, 0, 0);
      acc[mi][1] = __builtin_amdgcn_mfma_f32_16x16x32_bf16(a, bfr[1][kt], acc[mi][1], 0, 0, 0);
    }
  }
  // epilogue: row=(lane>>4)*4+q, col=lane&15
#pragma unroll
  for (int mi = 0; mi < 4; ++mi) {
#pragma unroll
    for (int q = 0; q < 4; ++q) {
      int row = i0 + mi * 16 + kg * 4 + q;
      bf16* orow = out + (size_t)(bt * N_ + row) * C_ + h * HD_;
      orow[dn]      = (bf16)acc[mi][0][q];
      orow[16 + dn] = (bf16)acc[mi][1][q];
    }
  }
}

// ---------- temporal attention (T=12) -> bf16 ----------
__global__ __launch_bounds__(64) void k_attn_t(const bf16* __restrict__ qkv,
                                               bf16* __restrict__ out) {
  __shared__ float q[T_][HD_], k[T_][HD_], v[T_][HD_];
  const int blk = blockIdx.x;
  const int bn = blk / NH_, h = blk - bn * NH_;
  const int tid = threadIdx.x;
  for (int idx = tid; idx < T_ * 3 * HD_; idx += 64) {
    int t = idx / 96, rem = idx - t * 96;
    int s = rem >> 5, d = rem & 31;
    float val = (float)qkv[(size_t)(bn * T_ + t) * QKV_ + s * C_ + h * HD_ + d];
    if (s == 0) q[t][d] = val;
    else if (s == 1) k[t][d] = val;
    else v[t][d] = val;
  }
  __syncthreads();
  if (tid < T_) {
    const int i = tid;
    float sv[T_];
    float m = -1e30f;
#pragma unroll
    for (int j = 0; j < T_; ++j) {
      float s = 0.f;
#pragma unroll
      for (int d = 0; d < HD_; ++d) s += q[i][d] * k[j][d];
      s *= 0.17677669529663687f;
      sv[j] = s; m = fmaxf(m, s);
    }
    float l = 0.f;
#pragma unroll
    for (int j = 0; j < T_; ++j) { sv[j] = __expf(sv[j] - m); l += sv[j]; }
    const float inv = 1.f / l;
    float o[HD_];
#pragma unroll
    for (int d = 0; d < HD_; ++d) o[d] = 0.f;
#pragma unroll
    for (int j = 0; j < T_; ++j)
#pragma unroll
      for (int d = 0; d < HD_; ++d) o[d] += sv[j] * v[j][d];
    bf16* orow = out + (size_t)(bn * T_ + i) * C_ + h * HD_;
#pragma unroll
    for (int d = 0; d < HD_; ++d) orow[d] = (bf16)(o[d] * inv);
  }
}

// ---------- residual with gate ----------
__global__ __launch_bounds__(128) void k_resid(const float* __restrict__ base,
                                               const float* __restrict__ add,
                                               const float* __restrict__ mod,
                                               float* __restrict__ out,
                                               int gate_chunk) {
  const int cc = blockIdx.x * 128 + threadIdx.x;
  const int r = blockIdx.y;
  const int bt = r >> 8;
  const size_t idx = (size_t)r * C_ + cc;
  out[idx] = base[idx] + mod[(size_t)bt * NINE_C + gate_chunk * C_ + cc] * add[idx];
}

// ---------- temporal residual scatter ----------
__global__ __launch_bounds__(128) void k_resid_t(const float* __restrict__ add,
                                                 const float* __restrict__ mod,
                                                 float* __restrict__ out) {
  const int cc = blockIdx.x * 128 + threadIdx.x;
  const int r = blockIdx.y;                 // r = bt*256 + n
  const int bt = r >> 8, n = r & 255;
  const int b = bt / T_, t = bt - b * T_;
  const size_t src = ((size_t)(b * N_ + n) * T_ + t) * C_ + cc;
  const size_t dst = (size_t)r * C_ + cc;
  out[dst] += mod[(size_t)bt * NINE_C + 5 * C_ + cc] * add[src];
}

extern "C" void kernel_launch(void* const* d_in, const int* in_sizes, int n_in,
                              void* d_out, int out_size, void* d_ws, size_t ws_size,
                              hipStream_t stream) {
  const float* x_in   = (const float*)d_in[0];
  const float* c_in   = (const float*)d_in[1];
  const float* relb   = (const float*)d_in[2];
  const float* w_ada  = (const float*)d_in[3];
  const float* b_ada  = (const float*)d_in[4];
  const float* wqkv_s = (const float*)d_in[5];
  const float* bqkv_s = (const float*)d_in[6];
  const float* wproj_s= (const float*)d_in[7];
  const float* bproj_s= (const float*)d_in[8];
  const float* wqkv_t = (const float*)d_in[9];
  const float* bqkv_t = (const float*)d_in[10];
  const float* wproj_t= (const float*)d_in[11];
  const float* bproj_t= (const float*)d_in[12];
  const float* w1     = (const float*)d_in[13];
  const float* b1     = (const float*)d_in[14];
  const float* w2     = (const float*)d_in[15];
  const float* b2     = (const float*)d_in[16];

  float* Xout = (float*)d_out;
  float* attn = (float*)d_out + (size_t)M_ * C_;

  char* ws = (char*)d_ws;
  float* mod  = (float*)ws;
  bf16*  Wb   = (bf16*)(ws + 1331200);
  bf16*  Bbuf = (bf16*)(ws + 6049792);
  float* Cbuf = (float*)(ws + 24924160);
  bf16*  Abuf = (bf16*)(ws + 62672896);

  bf16* wqkv_s_b = Wb;
  bf16* wproj_s_b = Wb + 442368;
  bf16* wqkv_t_b = Wb + 589824;
  bf16* wproj_t_b = Wb + 1032192;
  bf16* w1_b = Wb + 1179648;
  bf16* w2_b = Wb + 1769472;

  k_f2b<<<(442368/4 + 255)/256, 256, 0, stream>>>(wqkv_s, wqkv_s_b, 442368/4);
  k_f2b<<<(147456/4 + 255)/256, 256, 0, stream>>>(wproj_s, wproj_s_b, 147456/4);
  k_f2b<<<(442368/4 + 255)/256, 256, 0, stream>>>(wqkv_t, wqkv_t_b, 442368/4);
  k_f2b<<<(147456/4 + 255)/256, 256, 0, stream>>>(wproj_t, wproj_t_b, 147456/4);
  k_f2b<<<(589824/4 + 255)/256, 256, 0, stream>>>(w1, w1_b, 589824/4);
  k_f2b<<<(589824/4 + 255)/256, 256, 0, stream>>>(w2, w2_b, 589824/4);

  // 1. adaLN modulation
  k_adaln<<<BT_, 384, 0, stream>>>(c_in, w_ada, b_ada, mod);

  // 2. spatial
  k_ln_mod<<<M_ / 4, 256, 0, stream>>>(x_in, mod, Bbuf, 0, 1);
  mfma_gemm<bf16, 0><<<dim3(QKV_/128, M_/128), 256, 0, stream>>>(
      Bbuf, wqkv_s_b, bqkv_s, Abuf, M_, QKV_, C_);
  k_attn_sm2<<<BT_ * NH_, 256, 0, stream>>>(Abuf, relb, attn);
  k_attn_pv<<<BT_ * NH_, 256, 0, stream>>>(Abuf, attn, Bbuf);
  mfma_gemm<float, 0><<<dim3(C_/128, M_/128), 256, 0, stream>>>(
      Bbuf, wproj_s_b, bproj_s, Cbuf, M_, C_, C_);
  k_resid<<<dim3(3, M_), 128, 0, stream>>>(x_in, Cbuf, mod, Xout, 2);

  // 3. temporal
  k_ln_mod_t<<<M_ / 4, 256, 0, stream>>>(Xout, mod, Bbuf);
  mfma_gemm<bf16, 0><<<dim3(QKV_/128, M_/128), 256, 0, stream>>>(
      Bbuf, wqkv_t_b, bqkv_t, Abuf, M_, QKV_, C_);
  k_attn_t<<<B_ * N_ * NH_, 64, 0, stream>>>(Abuf, Bbuf);
  mfma_gemm<float, 0><<<dim3(C_/128, M_/128), 256, 0, stream>>>(
      Bbuf, wproj_t_b, bproj_t, Cbuf, M_, C_, C_);
  k_resid_t<<<dim3(3, M_), 128, 0, stream>>>(Cbuf, mod, Xout);

  // 4. MLP
  k_ln_mod<<<M_ / 4, 256, 0, stream>>>(Xout, mod, Bbuf, 6, 7);
  mfma_gemm<bf16, 1><<<dim3(MLP_/128, M_/128), 256, 0, stream>>>(
      Bbuf, w1_b, b1, Abuf, M_, MLP_, C_);
  mfma_gemm<float, 0><<<dim3(C_/128, M_/128), 256, 0, stream>>>(
      Abuf, w2_b, b2, Cbuf, M_, C_, MLP_);
  k_resid<<<dim3(3, M_), 128, 0, stream>>>(Xout, Cbuf, mod, Xout, 8);
}

// Round 4
// 799.757 us; speedup vs baseline: 4.4988x; 1.2871x over previous
//
#include <hip/hip_runtime.h>
#include <hip/hip_bf16.h>
#include <math.h>

typedef __bf16 bf16;
typedef __bf16 bf16x8 __attribute__((ext_vector_type(8)));
typedef __bf16 bf16x4 __attribute__((ext_vector_type(4)));
typedef float  f32x4  __attribute__((ext_vector_type(4)));

#define C_    384
#define NH_   12
#define HD_   32
#define MLP_  1536
#define B_    8
#define T_    12
#define N_    256
#define BT_   96
#define M_    24576
#define NINE_C 3456
#define QKV_  1152

__device__ __forceinline__ float wave_sum(float v) {
#pragma unroll
  for (int o = 32; o > 0; o >>= 1) v += __shfl_xor(v, o, 64);
  return v;
}

template <typename TO> __device__ __forceinline__ TO to_out(float v);
template <> __device__ __forceinline__ float to_out<float>(float v) { return v; }
template <> __device__ __forceinline__ bf16  to_out<bf16>(float v)  { return (bf16)v; }

// ---------- all f32 -> bf16 weight conversions in one kernel ----------
struct F2BArgs {
  const float* src[6];
  bf16* dst[6];
  int n4[6];
};
__global__ __launch_bounds__(256) void k_f2b_all(F2BArgs a) {
  const int seg = blockIdx.y;
  const int i = blockIdx.x * 256 + threadIdx.x;
  if (i < a.n4[seg]) {
    float4 v = ((const float4*)a.src[seg])[i];
    bf16x4 o;
    o[0] = (bf16)v.x; o[1] = (bf16)v.y; o[2] = (bf16)v.z; o[3] = (bf16)v.w;
    ((bf16x4*)a.dst[seg])[i] = o;
  }
}

// ---------- adaLN: mod = silu(c) @ w_adaln^T + b_adaln ----------
__global__ __launch_bounds__(384) void k_adaln(const float* __restrict__ c,
                                               const float* __restrict__ w,
                                               const float* __restrict__ b,
                                               float* __restrict__ mod) {
  __shared__ float sil[C_];
  const int bt = blockIdx.x, tid = threadIdx.x;
  float cv = c[bt * C_ + tid];
  sil[tid] = cv / (1.f + __expf(-cv));
  __syncthreads();
  for (int o = tid; o < NINE_C; o += 384) {
    const float* wr = w + (size_t)o * C_;
    float acc = b[o];
#pragma unroll 4
    for (int k = 0; k < C_; ++k) acc += sil[k] * wr[k];
    mod[(size_t)bt * NINE_C + o] = acc;
  }
}

// ---------- LayerNorm + adaLN modulate -> bf16 ----------
__global__ __launch_bounds__(256) void k_ln_mod(const float* __restrict__ x,
                                                const float* __restrict__ mod,
                                                bf16* __restrict__ out,
                                                int shift_chunk, int scale_chunk) {
  const int wave = threadIdx.x >> 6, lane = threadIdx.x & 63;
  const int r = blockIdx.x * 4 + wave;
  const float* xr = x + (size_t)r * C_;
  float v[6];
  float s = 0.f, ss = 0.f;
#pragma unroll
  for (int e = 0; e < 6; ++e) { v[e] = xr[lane + 64 * e]; s += v[e]; ss += v[e] * v[e]; }
  s = wave_sum(s); ss = wave_sum(ss);
  const float mean = s * (1.f / C_);
  const float var  = ss * (1.f / C_) - mean * mean;
  const float rs   = rsqrtf(var + 1e-6f);
  const int bt = r >> 8;
  const float* sh = mod + (size_t)bt * NINE_C + shift_chunk * C_;
  const float* sc = mod + (size_t)bt * NINE_C + scale_chunk * C_;
  bf16* orow = out + (size_t)r * C_;
#pragma unroll
  for (int e = 0; e < 6; ++e) {
    int cc = lane + 64 * e;
    orow[cc] = (bf16)((v[e] - mean) * rs * (1.f + sc[cc]) + sh[cc]);
  }
}

// ---------- temporal LN + modulate (gather) -> bf16 ----------
__global__ __launch_bounds__(256) void k_ln_mod_t(const float* __restrict__ x,
                                                  const float* __restrict__ mod,
                                                  bf16* __restrict__ out) {
  const int wave = threadIdx.x >> 6, lane = threadIdx.x & 63;
  const int rr = blockIdx.x * 4 + wave;          // rr = bn*12 + t
  const int bn = rr / T_, t = rr - bn * T_;
  const int b = bn >> 8, n = bn & 255;
  const int in_row = (b * T_ + t) * N_ + n;
  const int mrow   = b * T_ + t;
  const float* xr = x + (size_t)in_row * C_;
  float v[6];
  float s = 0.f, ss = 0.f;
#pragma unroll
  for (int e = 0; e < 6; ++e) { v[e] = xr[lane + 64 * e]; s += v[e]; ss += v[e] * v[e]; }
  s = wave_sum(s); ss = wave_sum(ss);
  const float mean = s * (1.f / C_);
  const float var  = ss * (1.f / C_) - mean * mean;
  const float rs   = rsqrtf(var + 1e-6f);
  const float* sh = mod + (size_t)mrow * NINE_C + 3 * C_;
  const float* sc = mod + (size_t)mrow * NINE_C + 4 * C_;
  bf16* orow = out + (size_t)rr * C_;
#pragma unroll
  for (int e = 0; e < 6; ++e) {
    int cc = lane + 64 * e;
    orow[cc] = (bf16)((v[e] - mean) * rs * (1.f + sc[cc]) + sh[cc]);
  }
}

// ---------- MFMA GEMM with fused epilogues ----------
// EPI 0: plain store (TO)
// EPI 1: exact GELU -> TO
// EPI 2: out_f32[r][c] = base[r][c] + mod[bt][gc*C+c] * v     (bt = m0>>8, constant per tile)
// EPI 3: temporal scatter: dst row from rr, out_f32[dst] += mod[btd][5C+c] * v
template <typename TO, int EPI>
__global__ __launch_bounds__(256) void mfma_gemm(const bf16* __restrict__ A,
                                                 const bf16* __restrict__ W,
                                                 const float* __restrict__ bias,
                                                 TO* __restrict__ out,
                                                 int M, int N, int K,
                                                 const float* __restrict__ base,
                                                 const float* __restrict__ mod,
                                                 int gc) {
  __shared__ bf16 As[128 * 64];
  __shared__ bf16 Bs[128 * 64];
  const int tid = threadIdx.x;
  const int w = tid >> 6, l = tid & 63;
  const int m0 = blockIdx.y * 128, n0 = blockIdx.x * 128;
  const int wr = w >> 1, wc = w & 1;
  f32x4 acc[4][4];
#pragma unroll
  for (int mi = 0; mi < 4; ++mi)
#pragma unroll
    for (int nj = 0; nj < 4; ++nj) acc[mi][nj] = (f32x4){0.f, 0.f, 0.f, 0.f};

  const int srow = tid >> 3;
  const int sc_  = tid & 7;

  for (int k0 = 0; k0 < K; k0 += 64) {
#pragma unroll
    for (int r = 0; r < 4; ++r) {
      int row = srow + 32 * r;
      bf16x8 av = *(const bf16x8*)(A + (size_t)(m0 + row) * K + k0 + sc_ * 8);
      bf16x8 bv = *(const bf16x8*)(W + (size_t)(n0 + row) * K + k0 + sc_ * 8);
      int sw = (sc_ ^ (row & 7)) << 4;
      *(bf16x8*)((char*)As + row * 128 + sw) = av;
      *(bf16x8*)((char*)Bs + row * 128 + sw) = bv;
    }
    __syncthreads();
#pragma unroll
    for (int kt = 0; kt < 2; ++kt) {
      bf16x8 a[4], b[4];
      const int cc = kt * 4 + (l >> 4);
#pragma unroll
      for (int mi = 0; mi < 4; ++mi) {
        int row = wr * 64 + mi * 16 + (l & 15);
        a[mi] = *(const bf16x8*)((const char*)As + row * 128 + ((cc ^ (row & 7)) << 4));
      }
#pragma unroll
      for (int nj = 0; nj < 4; ++nj) {
        int row = wc * 64 + nj * 16 + (l & 15);
        b[nj] = *(const bf16x8*)((const char*)Bs + row * 128 + ((cc ^ (row & 7)) << 4));
      }
#pragma unroll
      for (int mi = 0; mi < 4; ++mi)
#pragma unroll
        for (int nj = 0; nj < 4; ++nj)
          acc[mi][nj] = __builtin_amdgcn_mfma_f32_16x16x32_bf16(a[mi], b[nj], acc[mi][nj], 0, 0, 0);
    }
    __syncthreads();
  }
  const int btc = m0 >> 8;
#pragma unroll
  for (int nj = 0; nj < 4; ++nj) {
    int col = n0 + wc * 64 + nj * 16 + (l & 15);
    float bv = bias[col];
    float gv = 0.f;
    if (EPI == 2) gv = mod[(size_t)btc * NINE_C + gc * C_ + col];
#pragma unroll
    for (int mi = 0; mi < 4; ++mi) {
#pragma unroll
      for (int q = 0; q < 4; ++q) {
        int rrow = m0 + wr * 64 + mi * 16 + (l >> 4) * 4 + q;
        float v = acc[mi][nj][q] + bv;
        if (EPI == 0) {
          out[(size_t)rrow * N + col] = to_out<TO>(v);
        } else if (EPI == 1) {
          v = 0.5f * v * (1.f + erff(v * 0.70710678118654752f));
          out[(size_t)rrow * N + col] = to_out<TO>(v);
        } else if (EPI == 2) {
          ((float*)out)[(size_t)rrow * N + col] =
              base[(size_t)rrow * N + col] + gv * v;
        } else {
          int b = rrow / 3072;
          int rem = rrow - b * 3072;
          int n = rem / 12, t = rem - n * 12;
          int btd = b * 12 + t;
          size_t dst = ((size_t)btd * 256 + n) * N + col;
          float g = mod[(size_t)btd * NINE_C + 5 * C_ + col];
          ((float*)out)[dst] += g * v;
        }
      }
    }
  }
}

// ---------- fused spatial attention ----------
// per (bt,h): S = QK^T*scale + bias -> row softmax -> P to attn (f32, output) ->
// read P back (L2-hot) as A-frags -> O = P@V -> out bf16
__global__ __launch_bounds__(256) void k_attn_fused(const bf16* __restrict__ qkv,
                                                    const float* __restrict__ bias,
                                                    float* __restrict__ attn,
                                                    bf16* __restrict__ out) {
  __shared__ bf16 Vt[32 * 256];   // [d][k], rows 512B, XOR-swizzled 16B chunks
  const int blk = blockIdx.x;
  const int bt = blk / NH_, h = blk - bt * NH_;
  const int tid = threadIdx.x;
  // stage V transposed
#pragma unroll
  for (int r = 0; r < 4; ++r) {
    int id = tid + 256 * r;
    int j = id >> 2, c = id & 3;
    bf16x8 vv = *(const bf16x8*)(qkv + (size_t)(bt * N_ + j) * QKV_ + 2 * C_ + h * HD_ + c * 8);
    int kc = j >> 3, ke = j & 7;
#pragma unroll
    for (int i = 0; i < 8; ++i) {
      int d = c * 8 + i;
      *(bf16*)((char*)Vt + d * 512 + ((kc ^ (d & 7)) << 4) + ke * 2) = vv[i];
    }
  }
  const int w = tid >> 6, l = tid & 63;
  const int ln = l & 15, kg = l >> 4;
  // hoist K fragments: kfr[nj] = K[j = nj*16+ln][d = kg*8 .. +7]
  const bf16* kbase = qkv + (size_t)bt * N_ * QKV_ + C_ + h * HD_ + kg * 8;
  bf16x8 kfr[16];
#pragma unroll
  for (int nj = 0; nj < 16; ++nj)
    kfr[nj] = *(const bf16x8*)(kbase + (size_t)(nj * 16 + ln) * QKV_);
  __syncthreads();

  const float scale = 0.17677669529663687f;
  const float* bb = bias + (size_t)h * N_ * N_;
  float* Pb = attn + (size_t)blk * N_ * N_;
  const bf16* qbase = qkv + (size_t)bt * N_ * QKV_ + h * HD_ + kg * 8;

  for (int g = 0; g < 4; ++g) {
    const int i0 = w * 64 + g * 16;
    // QK^T: one MFMA per 16-col fragment (K = HD = 32)
    bf16x8 aq = *(const bf16x8*)(qbase + (size_t)(i0 + ln) * QKV_);
    f32x4 s[16];
#pragma unroll
    for (int nj = 0; nj < 16; ++nj)
      s[nj] = __builtin_amdgcn_mfma_f32_16x16x32_bf16(aq, kfr[nj], (f32x4){0.f,0.f,0.f,0.f}, 0, 0, 0);
    // softmax: row = i0 + kg*4 + q, col = nj*16 + ln
#pragma unroll
    for (int q = 0; q < 4; ++q) {
      const int row = i0 + kg * 4 + q;
      const float* br = bb + (size_t)row * N_ + ln;
      float v[16];
      float mx = -1e30f;
#pragma unroll
      for (int nj = 0; nj < 16; ++nj) {
        v[nj] = s[nj][q] * scale + br[nj * 16];
        mx = fmaxf(mx, v[nj]);
      }
#pragma unroll
      for (int o = 8; o > 0; o >>= 1) mx = fmaxf(mx, __shfl_xor(mx, o, 64));
      float sum = 0.f;
#pragma unroll
      for (int nj = 0; nj < 16; ++nj) { v[nj] = __expf(v[nj] - mx); sum += v[nj]; }
#pragma unroll
      for (int o = 8; o > 0; o >>= 1) sum += __shfl_xor(sum, o, 64);
      float inv = __frcp_rn(sum);
      float* pr = Pb + (size_t)row * N_ + ln;
#pragma unroll
      for (int nj = 0; nj < 16; ++nj) pr[nj * 16] = v[nj] * inv;
    }
    // drain P stores, then read back as A-frags (L2-hot) and do P@V
    asm volatile("s_waitcnt vmcnt(0)" ::: "memory");
    f32x4 o0 = (f32x4){0.f,0.f,0.f,0.f}, o1 = (f32x4){0.f,0.f,0.f,0.f};
    const float* prow = Pb + (size_t)(i0 + ln) * N_ + kg * 8;
#pragma unroll
    for (int kt = 0; kt < 8; ++kt) {
      float4 p0 = *(const float4*)(prow + kt * 32);
      float4 p1 = *(const float4*)(prow + kt * 32 + 4);
      bf16x8 a;
      a[0] = (bf16)p0.x; a[1] = (bf16)p0.y; a[2] = (bf16)p0.z; a[3] = (bf16)p0.w;
      a[4] = (bf16)p1.x; a[5] = (bf16)p1.y; a[6] = (bf16)p1.z; a[7] = (bf16)p1.w;
      int kc = kt * 4 + kg;
      bf16x8 b0 = *(const bf16x8*)((const char*)Vt + (size_t)ln * 512 + ((kc ^ (ln & 7)) << 4));
      bf16x8 b1 = *(const bf16x8*)((const char*)Vt + (size_t)(16 + ln) * 512 + ((kc ^ (ln & 7)) << 4));
      o0 = __builtin_amdgcn_mfma_f32_16x16x32_bf16(a, b0, o0, 0, 0, 0);
      o1 = __builtin_amdgcn_mfma_f32_16x16x32_bf16(a, b1, o1, 0, 0, 0);
    }
#pragma unroll
    for (int q = 0; q < 4; ++q) {
      int row = i0 + kg * 4 + q;
      bf16* orow = out + (size_t)(bt * N_ + row) * C_ + h * HD_;
      orow[ln]      = (bf16)o0[q];
      orow[16 + ln] = (bf16)o1[q];
    }
  }
}

// ---------- temporal attention (T=12) -> bf16 ----------
__global__ __launch_bounds__(64) void k_attn_t(const bf16* __restrict__ qkv,
                                               bf16* __restrict__ out) {
  __shared__ float q[T_][HD_], k[T_][HD_], v[T_][HD_];
  const int blk = blockIdx.x;
  const int bn = blk / NH_, h = blk - bn * NH_;
  const int tid = threadIdx.x;
  for (int idx = tid; idx < T_ * 3 * HD_; idx += 64) {
    int t = idx / 96, rem = idx - t * 96;
    int s = rem >> 5, d = rem & 31;
    float val = (float)qkv[(size_t)(bn * T_ + t) * QKV_ + s * C_ + h * HD_ + d];
    if (s == 0) q[t][d] = val;
    else if (s == 1) k[t][d] = val;
    else v[t][d] = val;
  }
  __syncthreads();
  if (tid < T_) {
    const int i = tid;
    float sv[T_];
    float m = -1e30f;
#pragma unroll
    for (int j = 0; j < T_; ++j) {
      float s = 0.f;
#pragma unroll
      for (int d = 0; d < HD_; ++d) s += q[i][d] * k[j][d];
      s *= 0.17677669529663687f;
      sv[j] = s; m = fmaxf(m, s);
    }
    float l = 0.f;
#pragma unroll
    for (int j = 0; j < T_; ++j) { sv[j] = __expf(sv[j] - m); l += sv[j]; }
    const float inv = 1.f / l;
    float o[HD_];
#pragma unroll
    for (int d = 0; d < HD_; ++d) o[d] = 0.f;
#pragma unroll
    for (int j = 0; j < T_; ++j)
#pragma unroll
      for (int d = 0; d < HD_; ++d) o[d] += sv[j] * v[j][d];
    bf16* orow = out + (size_t)(bn * T_ + i) * C_ + h * HD_;
#pragma unroll
    for (int d = 0; d < HD_; ++d) orow[d] = (bf16)(o[d] * inv);
  }
}

extern "C" void kernel_launch(void* const* d_in, const int* in_sizes, int n_in,
                              void* d_out, int out_size, void* d_ws, size_t ws_size,
                              hipStream_t stream) {
  const float* x_in   = (const float*)d_in[0];
  const float* c_in   = (const float*)d_in[1];
  const float* relb   = (const float*)d_in[2];
  const float* w_ada  = (const float*)d_in[3];
  const float* b_ada  = (const float*)d_in[4];
  const float* wqkv_s = (const float*)d_in[5];
  const float* bqkv_s = (const float*)d_in[6];
  const float* wproj_s= (const float*)d_in[7];
  const float* bproj_s= (const float*)d_in[8];
  const float* wqkv_t = (const float*)d_in[9];
  const float* bqkv_t = (const float*)d_in[10];
  const float* wproj_t= (const float*)d_in[11];
  const float* bproj_t= (const float*)d_in[12];
  const float* w1     = (const float*)d_in[13];
  const float* b1     = (const float*)d_in[14];
  const float* w2     = (const float*)d_in[15];
  const float* b2     = (const float*)d_in[16];

  float* Xout = (float*)d_out;
  float* attn = (float*)d_out + (size_t)M_ * C_;

  char* ws = (char*)d_ws;
  float* mod  = (float*)ws;
  bf16*  Wb   = (bf16*)(ws + 1331200);
  bf16*  Bbuf = (bf16*)(ws + 6049792);
  bf16*  Abuf = (bf16*)(ws + 62672896);

  bf16* wqkv_s_b  = Wb;
  bf16* wproj_s_b = Wb + 442368;
  bf16* wqkv_t_b  = Wb + 589824;
  bf16* wproj_t_b = Wb + 1032192;
  bf16* w1_b      = Wb + 1179648;
  bf16* w2_b      = Wb + 1769472;

  F2BArgs fa;
  fa.src[0] = wqkv_s; fa.dst[0] = wqkv_s_b;  fa.n4[0] = 110592;
  fa.src[1] = wproj_s; fa.dst[1] = wproj_s_b; fa.n4[1] = 36864;
  fa.src[2] = wqkv_t; fa.dst[2] = wqkv_t_b;  fa.n4[2] = 110592;
  fa.src[3] = wproj_t; fa.dst[3] = wproj_t_b; fa.n4[3] = 36864;
  fa.src[4] = w1;     fa.dst[4] = w1_b;      fa.n4[4] = 147456;
  fa.src[5] = w2;     fa.dst[5] = w2_b;      fa.n4[5] = 147456;
  k_f2b_all<<<dim3(576, 6), 256, 0, stream>>>(fa);

  // 1. adaLN modulation
  k_adaln<<<BT_, 384, 0, stream>>>(c_in, w_ada, b_ada, mod);

  // 2. spatial: LN+mod -> qkv -> fused attn (S, softmax, P out, P@V) -> proj+gated resid
  k_ln_mod<<<M_ / 4, 256, 0, stream>>>(x_in, mod, Bbuf, 0, 1);
  mfma_gemm<bf16, 0><<<dim3(QKV_/128, M_/128), 256, 0, stream>>>(
      Bbuf, wqkv_s_b, bqkv_s, Abuf, M_, QKV_, C_, nullptr, nullptr, 0);
  k_attn_fused<<<BT_ * NH_, 256, 0, stream>>>(Abuf, relb, attn, Bbuf);
  mfma_gemm<float, 2><<<dim3(C_/128, M_/128), 256, 0, stream>>>(
      Bbuf, wproj_s_b, bproj_s, (float*)Xout, M_, C_, C_, x_in, mod, 2);

  // 3. temporal: gather-LN -> qkv -> attn -> proj + fused scatter resid
  k_ln_mod_t<<<M_ / 4, 256, 0, stream>>>(Xout, mod, Bbuf);
  mfma_gemm<bf16, 0><<<dim3(QKV_/128, M_/128), 256, 0, stream>>>(
      Bbuf, wqkv_t_b, bqkv_t, Abuf, M_, QKV_, C_, nullptr, nullptr, 0);
  k_attn_t<<<B_ * N_ * NH_, 64, 0, stream>>>(Abuf, Bbuf);
  mfma_gemm<float, 3><<<dim3(C_/128, M_/128), 256, 0, stream>>>(
      Bbuf, wproj_t_b, bproj_t, (float*)Xout, M_, C_, C_, nullptr, mod, 5);

  // 4. MLP: LN+mod -> GEMM+GELU -> GEMM + fused gated resid (in-place)
  k_ln_mod<<<M_ / 4, 256, 0, stream>>>(Xout, mod, Bbuf, 6, 7);
  mfma_gemm<bf16, 1><<<dim3(MLP_/128, M_/128), 256, 0, stream>>>(
      Bbuf, w1_b, b1, Abuf, M_, MLP_, C_, nullptr, nullptr, 0);
  mfma_gemm<float, 2><<<dim3(C_/128, M_/128), 256, 0, stream>>>(
      Abuf, w2_b, b2, (float*)Xout, M_, C_, MLP_, Xout, mod, 8);
}

// Round 5
// 574.346 us; speedup vs baseline: 6.2644x; 1.3925x over previous
//
#include <hip/hip_runtime.h>
#include <hip/hip_bf16.h>
#include <math.h>

typedef __bf16 bf16;
typedef __bf16 bf16x8 __attribute__((ext_vector_type(8)));
typedef __bf16 bf16x4 __attribute__((ext_vector_type(4)));
typedef float  f32x4  __attribute__((ext_vector_type(4)));

#define C_    384
#define NH_   12
#define HD_   32
#define MLP_  1536
#define B_    8
#define T_    12
#define N_    256
#define BT_   96
#define M_    24576
#define NINE_C 3456
#define QKV_  1152

__device__ __forceinline__ float wave_sum(float v) {
#pragma unroll
  for (int o = 32; o > 0; o >>= 1) v += __shfl_xor(v, o, 64);
  return v;
}

template <typename TO> __device__ __forceinline__ TO to_out(float v);
template <> __device__ __forceinline__ float to_out<float>(float v) { return v; }
template <> __device__ __forceinline__ bf16  to_out<bf16>(float v)  { return (bf16)v; }

// ---------- all f32 -> bf16 weight conversions in one kernel ----------
struct F2BArgs {
  const float* src[7];
  bf16* dst[7];
  int n4[7];
};
__global__ __launch_bounds__(256) void k_f2b_all(F2BArgs a) {
  const int seg = blockIdx.y;
  const int i = blockIdx.x * 256 + threadIdx.x;
  if (i < a.n4[seg]) {
    float4 v = ((const float4*)a.src[seg])[i];
    bf16x4 o;
    o[0] = (bf16)v.x; o[1] = (bf16)v.y; o[2] = (bf16)v.z; o[3] = (bf16)v.w;
    ((bf16x4*)a.dst[seg])[i] = o;
  }
}

// ---------- silu(c) -> bf16, padded to 128 rows (rows 96..127 zero) ----------
__global__ __launch_bounds__(384) void k_silu(const float* __restrict__ c,
                                              bf16* __restrict__ out) {
  const int row = blockIdx.x, tid = threadIdx.x;
  float v = 0.f;
  if (row < BT_) {
    float cv = c[row * C_ + tid];
    v = cv / (1.f + __expf(-cv));
  }
  out[row * C_ + tid] = (bf16)v;
}

// ---------- LayerNorm + adaLN modulate -> bf16 ----------
__global__ __launch_bounds__(256) void k_ln_mod(const float* __restrict__ x,
                                                const float* __restrict__ mod,
                                                bf16* __restrict__ out,
                                                int shift_chunk, int scale_chunk) {
  const int wave = threadIdx.x >> 6, lane = threadIdx.x & 63;
  const int r = blockIdx.x * 4 + wave;
  const float* xr = x + (size_t)r * C_;
  float v[6];
  float s = 0.f, ss = 0.f;
#pragma unroll
  for (int e = 0; e < 6; ++e) { v[e] = xr[lane + 64 * e]; s += v[e]; ss += v[e] * v[e]; }
  s = wave_sum(s); ss = wave_sum(ss);
  const float mean = s * (1.f / C_);
  const float var  = ss * (1.f / C_) - mean * mean;
  const float rs   = rsqrtf(var + 1e-6f);
  const int bt = r >> 8;
  const float* sh = mod + (size_t)bt * NINE_C + shift_chunk * C_;
  const float* sc = mod + (size_t)bt * NINE_C + scale_chunk * C_;
  bf16* orow = out + (size_t)r * C_;
#pragma unroll
  for (int e = 0; e < 6; ++e) {
    int cc = lane + 64 * e;
    orow[cc] = (bf16)((v[e] - mean) * rs * (1.f + sc[cc]) + sh[cc]);
  }
}

// ---------- temporal LN + modulate (gather) -> bf16 ----------
__global__ __launch_bounds__(256) void k_ln_mod_t(const float* __restrict__ x,
                                                  const float* __restrict__ mod,
                                                  bf16* __restrict__ out) {
  const int wave = threadIdx.x >> 6, lane = threadIdx.x & 63;
  const int rr = blockIdx.x * 4 + wave;          // rr = bn*12 + t
  const int bn = rr / T_, t = rr - bn * T_;
  const int b = bn >> 8, n = bn & 255;
  const int in_row = (b * T_ + t) * N_ + n;
  const int mrow   = b * T_ + t;
  const float* xr = x + (size_t)in_row * C_;
  float v[6];
  float s = 0.f, ss = 0.f;
#pragma unroll
  for (int e = 0; e < 6; ++e) { v[e] = xr[lane + 64 * e]; s += v[e]; ss += v[e] * v[e]; }
  s = wave_sum(s); ss = wave_sum(ss);
  const float mean = s * (1.f / C_);
  const float var  = ss * (1.f / C_) - mean * mean;
  const float rs   = rsqrtf(var + 1e-6f);
  const float* sh = mod + (size_t)mrow * NINE_C + 3 * C_;
  const float* sc = mod + (size_t)mrow * NINE_C + 4 * C_;
  bf16* orow = out + (size_t)rr * C_;
#pragma unroll
  for (int e = 0; e < 6; ++e) {
    int cc = lane + 64 * e;
    orow[cc] = (bf16)((v[e] - mean) * rs * (1.f + sc[cc]) + sh[cc]);
  }
}

// ---------- MFMA GEMM with fused epilogues ----------
// EPI 0: plain store (TO)
// EPI 1: exact GELU -> TO
// EPI 2: out_f32[r][c] = base[r][c] + mod[bt][gc*C+c] * v
// EPI 3: temporal scatter: out_f32[dst] += mod[btd][5C+c] * v
template <typename TO, int EPI>
__global__ __launch_bounds__(256) void mfma_gemm(const bf16* __restrict__ A,
                                                 const bf16* __restrict__ W,
                                                 const float* __restrict__ bias,
                                                 TO* __restrict__ out,
                                                 int M, int N, int K,
                                                 const float* __restrict__ base,
                                                 const float* __restrict__ mod,
                                                 int gc) {
  __shared__ bf16 As[128 * 64];
  __shared__ bf16 Bs[128 * 64];
  const int tid = threadIdx.x;
  const int w = tid >> 6, l = tid & 63;
  const int m0 = blockIdx.y * 128, n0 = blockIdx.x * 128;
  const int wr = w >> 1, wc = w & 1;
  f32x4 acc[4][4];
#pragma unroll
  for (int mi = 0; mi < 4; ++mi)
#pragma unroll
    for (int nj = 0; nj < 4; ++nj) acc[mi][nj] = (f32x4){0.f, 0.f, 0.f, 0.f};

  const int srow = tid >> 3;
  const int sc_  = tid & 7;

  for (int k0 = 0; k0 < K; k0 += 64) {
#pragma unroll
    for (int r = 0; r < 4; ++r) {
      int row = srow + 32 * r;
      bf16x8 av = *(const bf16x8*)(A + (size_t)(m0 + row) * K + k0 + sc_ * 8);
      bf16x8 bv = *(const bf16x8*)(W + (size_t)(n0 + row) * K + k0 + sc_ * 8);
      int sw = (sc_ ^ (row & 7)) << 4;
      *(bf16x8*)((char*)As + row * 128 + sw) = av;
      *(bf16x8*)((char*)Bs + row * 128 + sw) = bv;
    }
    __syncthreads();
#pragma unroll
    for (int kt = 0; kt < 2; ++kt) {
      bf16x8 a[4], b[4];
      const int cc = kt * 4 + (l >> 4);
#pragma unroll
      for (int mi = 0; mi < 4; ++mi) {
        int row = wr * 64 + mi * 16 + (l & 15);
        a[mi] = *(const bf16x8*)((const char*)As + row * 128 + ((cc ^ (row & 7)) << 4));
      }
#pragma unroll
      for (int nj = 0; nj < 4; ++nj) {
        int row = wc * 64 + nj * 16 + (l & 15);
        b[nj] = *(const bf16x8*)((const char*)Bs + row * 128 + ((cc ^ (row & 7)) << 4));
      }
#pragma unroll
      for (int mi = 0; mi < 4; ++mi)
#pragma unroll
        for (int nj = 0; nj < 4; ++nj)
          acc[mi][nj] = __builtin_amdgcn_mfma_f32_16x16x32_bf16(a[mi], b[nj], acc[mi][nj], 0, 0, 0);
    }
    __syncthreads();
  }
  const int btc = m0 >> 8;
#pragma unroll
  for (int nj = 0; nj < 4; ++nj) {
    int col = n0 + wc * 64 + nj * 16 + (l & 15);
    float bv = bias[col];
    float gv = 0.f;
    if (EPI == 2) gv = mod[(size_t)btc * NINE_C + gc * C_ + col];
#pragma unroll
    for (int mi = 0; mi < 4; ++mi) {
#pragma unroll
      for (int q = 0; q < 4; ++q) {
        int rrow = m0 + wr * 64 + mi * 16 + (l >> 4) * 4 + q;
        float v = acc[mi][nj][q] + bv;
        if (EPI == 0) {
          out[(size_t)rrow * N + col] = to_out<TO>(v);
        } else if (EPI == 1) {
          v = 0.5f * v * (1.f + erff(v * 0.70710678118654752f));
          out[(size_t)rrow * N + col] = to_out<TO>(v);
        } else if (EPI == 2) {
          ((float*)out)[(size_t)rrow * N + col] =
              base[(size_t)rrow * N + col] + gv * v;
        } else {
          int b = rrow / 3072;
          int rem = rrow - b * 3072;
          int n = rem / 12, t = rem - n * 12;
          int btd = b * 12 + t;
          size_t dst = ((size_t)btd * 256 + n) * N + col;
          float g = mod[(size_t)btd * NINE_C + 5 * C_ + col];
          ((float*)out)[dst] += g * v;
        }
      }
    }
  }
}

// ---------- fused spatial attention ----------
__global__ __launch_bounds__(256) void k_attn_fused(const bf16* __restrict__ qkv,
                                                    const float* __restrict__ bias,
                                                    float* __restrict__ attn,
                                                    bf16* __restrict__ out) {
  __shared__ bf16 Vt[32 * 256];   // [d][k], rows 512B, XOR-swizzled 16B chunks
  const int blk = blockIdx.x;
  const int bt = blk / NH_, h = blk - bt * NH_;
  const int tid = threadIdx.x;
#pragma unroll
  for (int r = 0; r < 4; ++r) {
    int id = tid + 256 * r;
    int j = id >> 2, c = id & 3;
    bf16x8 vv = *(const bf16x8*)(qkv + (size_t)(bt * N_ + j) * QKV_ + 2 * C_ + h * HD_ + c * 8);
    int kc = j >> 3, ke = j & 7;
#pragma unroll
    for (int i = 0; i < 8; ++i) {
      int d = c * 8 + i;
      *(bf16*)((char*)Vt + d * 512 + ((kc ^ (d & 7)) << 4) + ke * 2) = vv[i];
    }
  }
  const int w = tid >> 6, l = tid & 63;
  const int ln = l & 15, kg = l >> 4;
  const bf16* kbase = qkv + (size_t)bt * N_ * QKV_ + C_ + h * HD_ + kg * 8;
  bf16x8 kfr[16];
#pragma unroll
  for (int nj = 0; nj < 16; ++nj)
    kfr[nj] = *(const bf16x8*)(kbase + (size_t)(nj * 16 + ln) * QKV_);
  __syncthreads();

  const float scale = 0.17677669529663687f;
  const float* bb = bias + (size_t)h * N_ * N_;
  float* Pb = attn + (size_t)blk * N_ * N_;
  const bf16* qbase = qkv + (size_t)bt * N_ * QKV_ + h * HD_ + kg * 8;

  for (int g = 0; g < 4; ++g) {
    const int i0 = w * 64 + g * 16;
    bf16x8 aq = *(const bf16x8*)(qbase + (size_t)(i0 + ln) * QKV_);
    f32x4 s[16];
#pragma unroll
    for (int nj = 0; nj < 16; ++nj)
      s[nj] = __builtin_amdgcn_mfma_f32_16x16x32_bf16(aq, kfr[nj], (f32x4){0.f,0.f,0.f,0.f}, 0, 0, 0);
#pragma unroll
    for (int q = 0; q < 4; ++q) {
      const int row = i0 + kg * 4 + q;
      const float* br = bb + (size_t)row * N_ + ln;
      float v[16];
      float mx = -1e30f;
#pragma unroll
      for (int nj = 0; nj < 16; ++nj) {
        v[nj] = s[nj][q] * scale + br[nj * 16];
        mx = fmaxf(mx, v[nj]);
      }
#pragma unroll
      for (int o = 8; o > 0; o >>= 1) mx = fmaxf(mx, __shfl_xor(mx, o, 64));
      float sum = 0.f;
#pragma unroll
      for (int nj = 0; nj < 16; ++nj) { v[nj] = __expf(v[nj] - mx); sum += v[nj]; }
#pragma unroll
      for (int o = 8; o > 0; o >>= 1) sum += __shfl_xor(sum, o, 64);
      float inv = __frcp_rn(sum);
      float* pr = Pb + (size_t)row * N_ + ln;
#pragma unroll
      for (int nj = 0; nj < 16; ++nj) pr[nj * 16] = v[nj] * inv;
    }
    asm volatile("s_waitcnt vmcnt(0)" ::: "memory");
    f32x4 o0 = (f32x4){0.f,0.f,0.f,0.f}, o1 = (f32x4){0.f,0.f,0.f,0.f};
    const float* prow = Pb + (size_t)(i0 + ln) * N_ + kg * 8;
#pragma unroll
    for (int kt = 0; kt < 8; ++kt) {
      float4 p0 = *(const float4*)(prow + kt * 32);
      float4 p1 = *(const float4*)(prow + kt * 32 + 4);
      bf16x8 a;
      a[0] = (bf16)p0.x; a[1] = (bf16)p0.y; a[2] = (bf16)p0.z; a[3] = (bf16)p0.w;
      a[4] = (bf16)p1.x; a[5] = (bf16)p1.y; a[6] = (bf16)p1.z; a[7] = (bf16)p1.w;
      int kc = kt * 4 + kg;
      bf16x8 b0 = *(const bf16x8*)((const char*)Vt + (size_t)ln * 512 + ((kc ^ (ln & 7)) << 4));
      bf16x8 b1 = *(const bf16x8*)((const char*)Vt + (size_t)(16 + ln) * 512 + ((kc ^ (ln & 7)) << 4));
      o0 = __builtin_amdgcn_mfma_f32_16x16x32_bf16(a, b0, o0, 0, 0, 0);
      o1 = __builtin_amdgcn_mfma_f32_16x16x32_bf16(a, b1, o1, 0, 0, 0);
    }
#pragma unroll
    for (int q = 0; q < 4; ++q) {
      int row = i0 + kg * 4 + q;
      bf16* orow = out + (size_t)(bt * N_ + row) * C_ + h * HD_;
      orow[ln]      = (bf16)o0[q];
      orow[16 + ln] = (bf16)o1[q];
    }
  }
}

// ---------- temporal attention (T=12) -> bf16 ----------
__global__ __launch_bounds__(64) void k_attn_t(const bf16* __restrict__ qkv,
                                               bf16* __restrict__ out) {
  __shared__ float q[T_][HD_], k[T_][HD_], v[T_][HD_];
  const int blk = blockIdx.x;
  const int bn = blk / NH_, h = blk - bn * NH_;
  const int tid = threadIdx.x;
  for (int idx = tid; idx < T_ * 3 * HD_; idx += 64) {
    int t = idx / 96, rem = idx - t * 96;
    int s = rem >> 5, d = rem & 31;
    float val = (float)qkv[(size_t)(bn * T_ + t) * QKV_ + s * C_ + h * HD_ + d];
    if (s == 0) q[t][d] = val;
    else if (s == 1) k[t][d] = val;
    else v[t][d] = val;
  }
  __syncthreads();
  if (tid < T_) {
    const int i = tid;
    float sv[T_];
    float m = -1e30f;
#pragma unroll
    for (int j = 0; j < T_; ++j) {
      float s = 0.f;
#pragma unroll
      for (int d = 0; d < HD_; ++d) s += q[i][d] * k[j][d];
      s *= 0.17677669529663687f;
      sv[j] = s; m = fmaxf(m, s);
    }
    float l = 0.f;
#pragma unroll
    for (int j = 0; j < T_; ++j) { sv[j] = __expf(sv[j] - m); l += sv[j]; }
    const float inv = 1.f / l;
    float o[HD_];
#pragma unroll
    for (int d = 0; d < HD_; ++d) o[d] = 0.f;
#pragma unroll
    for (int j = 0; j < T_; ++j)
#pragma unroll
      for (int d = 0; d < HD_; ++d) o[d] += sv[j] * v[j][d];
    bf16* orow = out + (size_t)(bn * T_ + i) * C_ + h * HD_;
#pragma unroll
    for (int d = 0; d < HD_; ++d) orow[d] = (bf16)(o[d] * inv);
  }
}

extern "C" void kernel_launch(void* const* d_in, const int* in_sizes, int n_in,
                              void* d_out, int out_size, void* d_ws, size_t ws_size,
                              hipStream_t stream) {
  const float* x_in   = (const float*)d_in[0];
  const float* c_in   = (const float*)d_in[1];
  const float* relb   = (const float*)d_in[2];
  const float* w_ada  = (const float*)d_in[3];
  const float* b_ada  = (const float*)d_in[4];
  const float* wqkv_s = (const float*)d_in[5];
  const float* bqkv_s = (const float*)d_in[6];
  const float* wproj_s= (const float*)d_in[7];
  const float* bproj_s= (const float*)d_in[8];
  const float* wqkv_t = (const float*)d_in[9];
  const float* bqkv_t = (const float*)d_in[10];
  const float* wproj_t= (const float*)d_in[11];
  const float* bproj_t= (const float*)d_in[12];
  const float* w1     = (const float*)d_in[13];
  const float* b1     = (const float*)d_in[14];
  const float* w2     = (const float*)d_in[15];
  const float* b2     = (const float*)d_in[16];

  float* Xout = (float*)d_out;
  float* attn = (float*)d_out + (size_t)M_ * C_;

  // ws layout (bytes):
  // mod    @ 0          128*3456*4 = 1,769,472   (rows 96..127 pad, never read)
  // silu_b @ 1,769,472  128*384*2  = 98,304
  // Wb     @ 1,867,776  3,686,400 bf16 = 7,372,800
  // Bbuf   @ 9,240,576  24576*384*2 = 18,874,368
  // Abuf   @ 28,114,944 24576*1536*2 = 75,497,472
  char* ws = (char*)d_ws;
  float* mod    = (float*)ws;
  bf16*  silu_b = (bf16*)(ws + 1769472);
  bf16*  Wb     = (bf16*)(ws + 1867776);
  bf16*  Bbuf   = (bf16*)(ws + 9240576);
  bf16*  Abuf   = (bf16*)(ws + 28114944);

  bf16* wqkv_s_b  = Wb;
  bf16* wproj_s_b = Wb + 442368;
  bf16* wqkv_t_b  = Wb + 589824;
  bf16* wproj_t_b = Wb + 1032192;
  bf16* w1_b      = Wb + 1179648;
  bf16* w2_b      = Wb + 1769472;
  bf16* wada_b    = Wb + 2359296;

  F2BArgs fa;
  fa.src[0] = wqkv_s;  fa.dst[0] = wqkv_s_b;  fa.n4[0] = 110592;
  fa.src[1] = wproj_s; fa.dst[1] = wproj_s_b; fa.n4[1] = 36864;
  fa.src[2] = wqkv_t;  fa.dst[2] = wqkv_t_b;  fa.n4[2] = 110592;
  fa.src[3] = wproj_t; fa.dst[3] = wproj_t_b; fa.n4[3] = 36864;
  fa.src[4] = w1;      fa.dst[4] = w1_b;      fa.n4[4] = 147456;
  fa.src[5] = w2;      fa.dst[5] = w2_b;      fa.n4[5] = 147456;
  fa.src[6] = w_ada;   fa.dst[6] = wada_b;    fa.n4[6] = 331776;
  k_f2b_all<<<dim3(1296, 7), 256, 0, stream>>>(fa);

  // 1. adaLN modulation via MFMA GEMM (M padded to 128)
  k_silu<<<128, 384, 0, stream>>>(c_in, silu_b);
  mfma_gemm<float, 0><<<dim3(NINE_C/128, 1), 256, 0, stream>>>(
      silu_b, wada_b, b_ada, mod, 128, NINE_C, C_, nullptr, nullptr, 0);

  // 2. spatial: LN+mod -> qkv -> fused attn -> proj+gated resid
  k_ln_mod<<<M_ / 4, 256, 0, stream>>>(x_in, mod, Bbuf, 0, 1);
  mfma_gemm<bf16, 0><<<dim3(QKV_/128, M_/128), 256, 0, stream>>>(
      Bbuf, wqkv_s_b, bqkv_s, Abuf, M_, QKV_, C_, nullptr, nullptr, 0);
  k_attn_fused<<<BT_ * NH_, 256, 0, stream>>>(Abuf, relb, attn, Bbuf);
  mfma_gemm<float, 2><<<dim3(C_/128, M_/128), 256, 0, stream>>>(
      Bbuf, wproj_s_b, bproj_s, (float*)Xout, M_, C_, C_, x_in, mod, 2);

  // 3. temporal: gather-LN -> qkv -> attn -> proj + fused scatter resid
  k_ln_mod_t<<<M_ / 4, 256, 0, stream>>>(Xout, mod, Bbuf);
  mfma_gemm<bf16, 0><<<dim3(QKV_/128, M_/128), 256, 0, stream>>>(
      Bbuf, wqkv_t_b, bqkv_t, Abuf, M_, QKV_, C_, nullptr, nullptr, 0);
  k_attn_t<<<B_ * N_ * NH_, 64, 0, stream>>>(Abuf, Bbuf);
  mfma_gemm<float, 3><<<dim3(C_/128, M_/128), 256, 0, stream>>>(
      Bbuf, wproj_t_b, bproj_t, (float*)Xout, M_, C_, C_, nullptr, mod, 5);

  // 4. MLP: LN+mod -> GEMM+GELU -> GEMM + fused gated resid (in-place)
  k_ln_mod<<<M_ / 4, 256, 0, stream>>>(Xout, mod, Bbuf, 6, 7);
  mfma_gemm<bf16, 1><<<dim3(MLP_/128, M_/128), 256, 0, stream>>>(
      Bbuf, w1_b, b1, Abuf, M_, MLP_, C_, nullptr, nullptr, 0);
  mfma_gemm<float, 2><<<dim3(C_/128, M_/128), 256, 0, stream>>>(
      Abuf, w2_b, b2, (float*)Xout, M_, C_, MLP_, Xout, mod, 8);
}

// Round 6
// 526.053 us; speedup vs baseline: 6.8395x; 1.0918x over previous
//
#include <hip/hip_runtime.h>
#include <hip/hip_bf16.h>
#include <math.h>

typedef __bf16 bf16;
typedef __bf16 bf16x8 __attribute__((ext_vector_type(8)));
typedef __bf16 bf16x4 __attribute__((ext_vector_type(4)));
typedef float  f32x4  __attribute__((ext_vector_type(4)));

#define C_    384
#define NH_   12
#define HD_   32
#define MLP_  1536
#define B_    8
#define T_    12
#define N_    256
#define BT_   96
#define M_    24576
#define NINE_C 3456
#define QKV_  1152

#define GLOAD16(gptr, lptr)                                                \
  __builtin_amdgcn_global_load_lds(                                       \
      (const __attribute__((address_space(1))) void*)(gptr),              \
      (__attribute__((address_space(3))) void*)(lptr), 16, 0, 0)

__device__ __forceinline__ float wave_sum(float v) {
#pragma unroll
  for (int o = 32; o > 0; o >>= 1) v += __shfl_xor(v, o, 64);
  return v;
}

template <typename TO> __device__ __forceinline__ TO to_out(float v);
template <> __device__ __forceinline__ float to_out<float>(float v) { return v; }
template <> __device__ __forceinline__ bf16  to_out<bf16>(float v)  { return (bf16)v; }

// ---------- all f32 -> bf16 weight conversions in one kernel ----------
struct F2BArgs {
  const float* src[7];
  bf16* dst[7];
  int n4[7];
};
__global__ __launch_bounds__(256) void k_f2b_all(F2BArgs a) {
  const int seg = blockIdx.y;
  const int i = blockIdx.x * 256 + threadIdx.x;
  if (i < a.n4[seg]) {
    float4 v = ((const float4*)a.src[seg])[i];
    bf16x4 o;
    o[0] = (bf16)v.x; o[1] = (bf16)v.y; o[2] = (bf16)v.z; o[3] = (bf16)v.w;
    ((bf16x4*)a.dst[seg])[i] = o;
  }
}

// ---------- silu(c) -> bf16, padded to 128 rows (rows 96..127 zero) ----------
__global__ __launch_bounds__(384) void k_silu(const float* __restrict__ c,
                                              bf16* __restrict__ out) {
  const int row = blockIdx.x, tid = threadIdx.x;
  float v = 0.f;
  if (row < BT_) {
    float cv = c[row * C_ + tid];
    v = cv / (1.f + __expf(-cv));
  }
  out[row * C_ + tid] = (bf16)v;
}

// ---------- LayerNorm + adaLN modulate -> bf16 ----------
__global__ __launch_bounds__(256) void k_ln_mod(const float* __restrict__ x,
                                                const float* __restrict__ mod,
                                                bf16* __restrict__ out,
                                                int shift_chunk, int scale_chunk) {
  const int wave = threadIdx.x >> 6, lane = threadIdx.x & 63;
  const int r = blockIdx.x * 4 + wave;
  const float* xr = x + (size_t)r * C_;
  float v[6];
  float s = 0.f, ss = 0.f;
#pragma unroll
  for (int e = 0; e < 6; ++e) { v[e] = xr[lane + 64 * e]; s += v[e]; ss += v[e] * v[e]; }
  s = wave_sum(s); ss = wave_sum(ss);
  const float mean = s * (1.f / C_);
  const float var  = ss * (1.f / C_) - mean * mean;
  const float rs   = rsqrtf(var + 1e-6f);
  const int bt = r >> 8;
  const float* sh = mod + (size_t)bt * NINE_C + shift_chunk * C_;
  const float* sc = mod + (size_t)bt * NINE_C + scale_chunk * C_;
  bf16* orow = out + (size_t)r * C_;
#pragma unroll
  for (int e = 0; e < 6; ++e) {
    int cc = lane + 64 * e;
    orow[cc] = (bf16)((v[e] - mean) * rs * (1.f + sc[cc]) + sh[cc]);
  }
}

// ---------- temporal LN + modulate (gather) -> bf16 ----------
__global__ __launch_bounds__(256) void k_ln_mod_t(const float* __restrict__ x,
                                                  const float* __restrict__ mod,
                                                  bf16* __restrict__ out) {
  const int wave = threadIdx.x >> 6, lane = threadIdx.x & 63;
  const int rr = blockIdx.x * 4 + wave;          // rr = bn*12 + t
  const int bn = rr / T_, t = rr - bn * T_;
  const int b = bn >> 8, n = bn & 255;
  const int in_row = (b * T_ + t) * N_ + n;
  const int mrow   = b * T_ + t;
  const float* xr = x + (size_t)in_row * C_;
  float v[6];
  float s = 0.f, ss = 0.f;
#pragma unroll
  for (int e = 0; e < 6; ++e) { v[e] = xr[lane + 64 * e]; s += v[e]; ss += v[e] * v[e]; }
  s = wave_sum(s); ss = wave_sum(ss);
  const float mean = s * (1.f / C_);
  const float var  = ss * (1.f / C_) - mean * mean;
  const float rs   = rsqrtf(var + 1e-6f);
  const float* sh = mod + (size_t)mrow * NINE_C + 3 * C_;
  const float* sc = mod + (size_t)mrow * NINE_C + 4 * C_;
  bf16* orow = out + (size_t)rr * C_;
#pragma unroll
  for (int e = 0; e < 6; ++e) {
    int cc = lane + 64 * e;
    orow[cc] = (bf16)((v[e] - mean) * rs * (1.f + sc[cc]) + sh[cc]);
  }
}

// ---------- MFMA GEMM, global_load_lds staging + XCD swizzle ----------
// 1D grid; tile map: t -> (m_tile = t/ntx, n_tile = t%ntx).
// LDS linear rows 128B; source address pre-swizzled so read-side XOR works.
// EPI 0: plain store; 1: exact GELU; 2: gated residual; 3: temporal scatter resid.
template <typename TO, int EPI>
__global__ __launch_bounds__(256) void mfma_gemm(const bf16* __restrict__ A,
                                                 const bf16* __restrict__ W,
                                                 const float* __restrict__ bias,
                                                 TO* __restrict__ out,
                                                 int M, int N, int K,
                                                 const float* __restrict__ base,
                                                 const float* __restrict__ mod,
                                                 int gc, int ntx) {
  __shared__ bf16 As[128 * 64];
  __shared__ bf16 Bs[128 * 64];
  const int tid = threadIdx.x;
  const int w = tid >> 6, l = tid & 63;
  // bijective XCD swizzle (m204): consecutive tiles -> same XCD
  const int nwg = gridDim.x;
  const int q8 = nwg >> 3, r8 = nwg & 7;
  const int xcd = blockIdx.x & 7, idx = blockIdx.x >> 3;
  const int t = (xcd < r8 ? xcd * (q8 + 1) : r8 * (q8 + 1) + (xcd - r8) * q8) + idx;
  const int m0 = (t / ntx) * 128, n0 = (t % ntx) * 128;
  const int wr = w >> 1, wc = w & 1;
  f32x4 acc[4][4];
#pragma unroll
  for (int mi = 0; mi < 4; ++mi)
#pragma unroll
    for (int nj = 0; nj < 4; ++nj) acc[mi][nj] = (f32x4){0.f, 0.f, 0.f, 0.f};

  const int srow8 = l >> 3;     // row within 8-row group
  const int c8    = l & 7;      // chunk position in LDS row

  for (int k0 = 0; k0 < K; k0 += 64) {
#pragma unroll
    for (int i = 0; i < 4; ++i) {
      int row = w * 32 + i * 8 + srow8;
      int sc = c8 ^ (row & 7);                 // pre-swizzled source chunk
      GLOAD16(A + (size_t)(m0 + row) * K + k0 + sc * 8,
              (char*)As + (w * 32 + i * 8) * 128);
      GLOAD16(W + (size_t)(n0 + row) * K + k0 + sc * 8,
              (char*)Bs + (w * 32 + i * 8) * 128);
    }
    __syncthreads();
#pragma unroll
    for (int kt = 0; kt < 2; ++kt) {
      bf16x8 a[4], b[4];
      const int cc = kt * 4 + (l >> 4);
#pragma unroll
      for (int mi = 0; mi < 4; ++mi) {
        int row = wr * 64 + mi * 16 + (l & 15);
        a[mi] = *(const bf16x8*)((const char*)As + row * 128 + ((cc ^ (row & 7)) << 4));
      }
#pragma unroll
      for (int nj = 0; nj < 4; ++nj) {
        int row = wc * 64 + nj * 16 + (l & 15);
        b[nj] = *(const bf16x8*)((const char*)Bs + row * 128 + ((cc ^ (row & 7)) << 4));
      }
#pragma unroll
      for (int mi = 0; mi < 4; ++mi)
#pragma unroll
        for (int nj = 0; nj < 4; ++nj)
          acc[mi][nj] = __builtin_amdgcn_mfma_f32_16x16x32_bf16(a[mi], b[nj], acc[mi][nj], 0, 0, 0);
    }
    __syncthreads();
  }
  const int btc = m0 >> 8;
#pragma unroll
  for (int nj = 0; nj < 4; ++nj) {
    int col = n0 + wc * 64 + nj * 16 + (l & 15);
    float bv = bias[col];
    float gv = 0.f;
    if (EPI == 2) gv = mod[(size_t)btc * NINE_C + gc * C_ + col];
#pragma unroll
    for (int mi = 0; mi < 4; ++mi) {
#pragma unroll
      for (int q = 0; q < 4; ++q) {
        int rrow = m0 + wr * 64 + mi * 16 + (l >> 4) * 4 + q;
        float v = acc[mi][nj][q] + bv;
        if (EPI == 0) {
          out[(size_t)rrow * N + col] = to_out<TO>(v);
        } else if (EPI == 1) {
          v = 0.5f * v * (1.f + erff(v * 0.70710678118654752f));
          out[(size_t)rrow * N + col] = to_out<TO>(v);
        } else if (EPI == 2) {
          ((float*)out)[(size_t)rrow * N + col] =
              base[(size_t)rrow * N + col] + gv * v;
        } else {
          int b = rrow / 3072;
          int rem = rrow - b * 3072;
          int n = rem / 12, tt = rem - n * 12;
          int btd = b * 12 + tt;
          size_t dst = ((size_t)btd * 256 + n) * N + col;
          float g = mod[(size_t)btd * NINE_C + 5 * C_ + col];
          ((float*)out)[dst] += g * v;
        }
      }
    }
  }
}

// ---------- fused spatial attention ----------
// S = QK^T*scale + bias -> softmax -> P: f32 to global (output, fire-and-forget)
//                                     + bf16 to LDS -> PV MFMA from LDS.
__global__ __launch_bounds__(256) void k_attn_fused(const bf16* __restrict__ qkv,
                                                    const float* __restrict__ bias,
                                                    float* __restrict__ attn,
                                                    bf16* __restrict__ out) {
  __shared__ bf16 Vt[32 * 256];        // [d][k], rows 512B, XOR-swizzled 16B chunks
  __shared__ bf16 Pl[4][16][260];      // per-wave P tile, padded rows (520B)
  const int blk = blockIdx.x;
  const int bt = blk / NH_, h = blk - bt * NH_;
  const int tid = threadIdx.x;
#pragma unroll
  for (int r = 0; r < 4; ++r) {
    int id = tid + 256 * r;
    int j = id >> 2, c = id & 3;
    bf16x8 vv = *(const bf16x8*)(qkv + (size_t)(bt * N_ + j) * QKV_ + 2 * C_ + h * HD_ + c * 8);
    int kc = j >> 3, ke = j & 7;
#pragma unroll
    for (int i = 0; i < 8; ++i) {
      int d = c * 8 + i;
      *(bf16*)((char*)Vt + d * 512 + ((kc ^ (d & 7)) << 4) + ke * 2) = vv[i];
    }
  }
  const int w = tid >> 6, l = tid & 63;
  const int ln = l & 15, kg = l >> 4;
  const bf16* kbase = qkv + (size_t)bt * N_ * QKV_ + C_ + h * HD_ + kg * 8;
  bf16x8 kfr[16];
#pragma unroll
  for (int nj = 0; nj < 16; ++nj)
    kfr[nj] = *(const bf16x8*)(kbase + (size_t)(nj * 16 + ln) * QKV_);
  __syncthreads();

  const float scale = 0.17677669529663687f;
  const float* bb = bias + (size_t)h * N_ * N_;
  float* Pb = attn + (size_t)blk * N_ * N_;
  const bf16* qbase = qkv + (size_t)bt * N_ * QKV_ + h * HD_ + kg * 8;
  char* Pw = (char*)&Pl[w][0][0];

  for (int g = 0; g < 4; ++g) {
    const int i0 = w * 64 + g * 16;
    bf16x8 aq = *(const bf16x8*)(qbase + (size_t)(i0 + ln) * QKV_);
    f32x4 s[16];
#pragma unroll
    for (int nj = 0; nj < 16; ++nj)
      s[nj] = __builtin_amdgcn_mfma_f32_16x16x32_bf16(aq, kfr[nj], (f32x4){0.f,0.f,0.f,0.f}, 0, 0, 0);
#pragma unroll
    for (int q = 0; q < 4; ++q) {
      const int lr = kg * 4 + q;           // local row in wave's 16-row group
      const int row = i0 + lr;
      const float* br = bb + (size_t)row * N_ + ln;
      float v[16];
      float mx = -1e30f;
#pragma unroll
      for (int nj = 0; nj < 16; ++nj) {
        v[nj] = s[nj][q] * scale + br[nj * 16];
        mx = fmaxf(mx, v[nj]);
      }
#pragma unroll
      for (int o = 8; o > 0; o >>= 1) mx = fmaxf(mx, __shfl_xor(mx, o, 64));
      float sum = 0.f;
#pragma unroll
      for (int nj = 0; nj < 16; ++nj) { v[nj] = __expf(v[nj] - mx); sum += v[nj]; }
#pragma unroll
      for (int o = 8; o > 0; o >>= 1) sum += __shfl_xor(sum, o, 64);
      float inv = __frcp_rn(sum);
      float* pr = Pb + (size_t)row * N_ + ln;
#pragma unroll
      for (int nj = 0; nj < 16; ++nj) {
        float p = v[nj] * inv;
        pr[nj * 16] = p;                                   // output write (no wait)
        *(bf16*)(Pw + lr * 520 + (ln + 16 * nj) * 2) = (bf16)p;  // LDS for PV
      }
    }
    // PV from LDS: A-frag = P[i0+ln][kt*32 + kg*8 .. +7]
    f32x4 o0 = (f32x4){0.f,0.f,0.f,0.f}, o1 = (f32x4){0.f,0.f,0.f,0.f};
#pragma unroll
    for (int kt = 0; kt < 8; ++kt) {
      bf16x8 a = *(const bf16x8*)(Pw + ln * 520 + kt * 64 + kg * 16);
      int kc = kt * 4 + kg;
      bf16x8 b0 = *(const bf16x8*)((const char*)Vt + (size_t)ln * 512 + ((kc ^ (ln & 7)) << 4));
      bf16x8 b1 = *(const bf16x8*)((const char*)Vt + (size_t)(16 + ln) * 512 + ((kc ^ (ln & 7)) << 4));
      o0 = __builtin_amdgcn_mfma_f32_16x16x32_bf16(a, b0, o0, 0, 0, 0);
      o1 = __builtin_amdgcn_mfma_f32_16x16x32_bf16(a, b1, o1, 0, 0, 0);
    }
#pragma unroll
    for (int q = 0; q < 4; ++q) {
      int row = i0 + kg * 4 + q;
      bf16* orow = out + (size_t)(bt * N_ + row) * C_ + h * HD_;
      orow[ln]      = (bf16)o0[q];
      orow[16 + ln] = (bf16)o1[q];
    }
  }
}

// ---------- temporal attention (T=12) -> bf16 ----------
__global__ __launch_bounds__(64) void k_attn_t(const bf16* __restrict__ qkv,
                                               bf16* __restrict__ out) {
  __shared__ float q[T_][HD_], k[T_][HD_], v[T_][HD_];
  const int blk = blockIdx.x;
  const int bn = blk / NH_, h = blk - bn * NH_;
  const int tid = threadIdx.x;
  for (int idx = tid; idx < T_ * 3 * HD_; idx += 64) {
    int t = idx / 96, rem = idx - t * 96;
    int s = rem >> 5, d = rem & 31;
    float val = (float)qkv[(size_t)(bn * T_ + t) * QKV_ + s * C_ + h * HD_ + d];
    if (s == 0) q[t][d] = val;
    else if (s == 1) k[t][d] = val;
    else v[t][d] = val;
  }
  __syncthreads();
  if (tid < T_) {
    const int i = tid;
    float sv[T_];
    float m = -1e30f;
#pragma unroll
    for (int j = 0; j < T_; ++j) {
      float s = 0.f;
#pragma unroll
      for (int d = 0; d < HD_; ++d) s += q[i][d] * k[j][d];
      s *= 0.17677669529663687f;
      sv[j] = s; m = fmaxf(m, s);
    }
    float l = 0.f;
#pragma unroll
    for (int j = 0; j < T_; ++j) { sv[j] = __expf(sv[j] - m); l += sv[j]; }
    const float inv = 1.f / l;
    float o[HD_];
#pragma unroll
    for (int d = 0; d < HD_; ++d) o[d] = 0.f;
#pragma unroll
    for (int j = 0; j < T_; ++j)
#pragma unroll
      for (int d = 0; d < HD_; ++d) o[d] += sv[j] * v[j][d];
    bf16* orow = out + (size_t)(bn * T_ + i) * C_ + h * HD_;
#pragma unroll
    for (int d = 0; d < HD_; ++d) orow[d] = (bf16)(o[d] * inv);
  }
}

extern "C" void kernel_launch(void* const* d_in, const int* in_sizes, int n_in,
                              void* d_out, int out_size, void* d_ws, size_t ws_size,
                              hipStream_t stream) {
  const float* x_in   = (const float*)d_in[0];
  const float* c_in   = (const float*)d_in[1];
  const float* relb   = (const float*)d_in[2];
  const float* w_ada  = (const float*)d_in[3];
  const float* b_ada  = (const float*)d_in[4];
  const float* wqkv_s = (const float*)d_in[5];
  const float* bqkv_s = (const float*)d_in[6];
  const float* wproj_s= (const float*)d_in[7];
  const float* bproj_s= (const float*)d_in[8];
  const float* wqkv_t = (const float*)d_in[9];
  const float* bqkv_t = (const float*)d_in[10];
  const float* wproj_t= (const float*)d_in[11];
  const float* bproj_t= (const float*)d_in[12];
  const float* w1     = (const float*)d_in[13];
  const float* b1     = (const float*)d_in[14];
  const float* w2     = (const float*)d_in[15];
  const float* b2     = (const float*)d_in[16];

  float* Xout = (float*)d_out;
  float* attn = (float*)d_out + (size_t)M_ * C_;

  // ws layout (bytes):
  // mod    @ 0          128*3456*4 = 1,769,472   (rows 96..127 pad, never read)
  // silu_b @ 1,769,472  128*384*2  = 98,304
  // Wb     @ 1,867,776  3,686,400 bf16 = 7,372,800
  // Bbuf   @ 9,240,576  24576*384*2 = 18,874,368
  // Abuf   @ 28,114,944 24576*1536*2 = 75,497,472
  char* ws = (char*)d_ws;
  float* mod    = (float*)ws;
  bf16*  silu_b = (bf16*)(ws + 1769472);
  bf16*  Wb     = (bf16*)(ws + 1867776);
  bf16*  Bbuf   = (bf16*)(ws + 9240576);
  bf16*  Abuf   = (bf16*)(ws + 28114944);

  bf16* wqkv_s_b  = Wb;
  bf16* wproj_s_b = Wb + 442368;
  bf16* wqkv_t_b  = Wb + 589824;
  bf16* wproj_t_b = Wb + 1032192;
  bf16* w1_b      = Wb + 1179648;
  bf16* w2_b      = Wb + 1769472;
  bf16* wada_b    = Wb + 2359296;

  F2BArgs fa;
  fa.src[0] = wqkv_s;  fa.dst[0] = wqkv_s_b;  fa.n4[0] = 110592;
  fa.src[1] = wproj_s; fa.dst[1] = wproj_s_b; fa.n4[1] = 36864;
  fa.src[2] = wqkv_t;  fa.dst[2] = wqkv_t_b;  fa.n4[2] = 110592;
  fa.src[3] = wproj_t; fa.dst[3] = wproj_t_b; fa.n4[3] = 36864;
  fa.src[4] = w1;      fa.dst[4] = w1_b;      fa.n4[4] = 147456;
  fa.src[5] = w2;      fa.dst[5] = w2_b;      fa.n4[5] = 147456;
  fa.src[6] = w_ada;   fa.dst[6] = wada_b;    fa.n4[6] = 331776;
  k_f2b_all<<<dim3(1296, 7), 256, 0, stream>>>(fa);

  // 1. adaLN modulation via MFMA GEMM (M padded to 128)
  k_silu<<<128, 384, 0, stream>>>(c_in, silu_b);
  mfma_gemm<float, 0><<<27, 256, 0, stream>>>(
      silu_b, wada_b, b_ada, mod, 128, NINE_C, C_, nullptr, nullptr, 0, 27);

  // 2. spatial: LN+mod -> qkv -> fused attn -> proj+gated resid
  k_ln_mod<<<M_ / 4, 256, 0, stream>>>(x_in, mod, Bbuf, 0, 1);
  mfma_gemm<bf16, 0><<<(QKV_/128)*(M_/128), 256, 0, stream>>>(
      Bbuf, wqkv_s_b, bqkv_s, Abuf, M_, QKV_, C_, nullptr, nullptr, 0, QKV_/128);
  k_attn_fused<<<BT_ * NH_, 256, 0, stream>>>(Abuf, relb, attn, Bbuf);
  mfma_gemm<float, 2><<<(C_/128)*(M_/128), 256, 0, stream>>>(
      Bbuf, wproj_s_b, bproj_s, (float*)Xout, M_, C_, C_, x_in, mod, 2, C_/128);

  // 3. temporal: gather-LN -> qkv -> attn -> proj + fused scatter resid
  k_ln_mod_t<<<M_ / 4, 256, 0, stream>>>(Xout, mod, Bbuf);
  mfma_gemm<bf16, 0><<<(QKV_/128)*(M_/128), 256, 0, stream>>>(
      Bbuf, wqkv_t_b, bqkv_t, Abuf, M_, QKV_, C_, nullptr, nullptr, 0, QKV_/128);
  k_attn_t<<<B_ * N_ * NH_, 64, 0, stream>>>(Abuf, Bbuf);
  mfma_gemm<float, 3><<<(C_/128)*(M_/128), 256, 0, stream>>>(
      Bbuf, wproj_t_b, bproj_t, (float*)Xout, M_, C_, C_, nullptr, mod, 5, C_/128);

  // 4. MLP: LN+mod -> GEMM+GELU -> GEMM + fused gated resid (in-place)
  k_ln_mod<<<M_ / 4, 256, 0, stream>>>(Xout, mod, Bbuf, 6, 7);
  mfma_gemm<bf16, 1><<<(MLP_/128)*(M_/128), 256, 0, stream>>>(
      Bbuf, w1_b, b1, Abuf, M_, MLP_, C_, nullptr, nullptr, 0, MLP_/128);
  mfma_gemm<float, 2><<<(C_/128)*(M_/128), 256, 0, stream>>>(
      Abuf, w2_b, b2, (float*)Xout, M_, C_, MLP_, Xout, mod, 8, C_/128);
}